// Round 8
// baseline (680.457 us; speedup 1.0000x reference)
//
#include <hip/hip_runtime.h>
#include <hip/hip_bf16.h>
#include <math.h>

// ---------------------------------------------------------------------------
// Linear_Transformer on MI355X (gfx950). fp32 I/O, bf16 MFMA internals,
// fp32 residual stream.
// Round 18: gemm256 K-loop rebuilt to the m201-faithful phase shape after
// R7's null showed barriers weren't the limiter. Diagnosis: staging duty
// cycle ~40% (implied 7 B/cyc/CU vs m201's 19) because stages were spread
// ph1-ph3 -> last half-tile issued at ph3 had ZERO phase cover before the
// tile-boundary vmcnt -> burst-then-drain every tile. Fix: (1) all 8 gloads
// of tile t+1 issued in ONE burst at ph0 of tile t (3 phases of cover;
// single vmcnt(0) at ph3-end waits on ~3k-cycle-old loads); (2) m201 phase
// shape: reads issued BEFORE a barrier, lgkmcnt(0)+MFMA after it (read
// latency hides under barrier wait; 2 barriers/phase). Ledger: stage(nb)@ph0
// vs nb reads: drained at t-1 ph3 lgkm0 + barrier; cb reads vs t+1 ph0
// stage(cb): separated by t ph3 lgkm0 + tile-end barrier; vmcnt(0)@ph3
// covers loads issued @ph0. Epilogue + all other kernels unchanged from R7.
// ---------------------------------------------------------------------------

typedef __hip_bfloat16 bf16;
typedef __attribute__((ext_vector_type(8))) short short8;   // 8 bf16 (MFMA A/B frag)
typedef __attribute__((ext_vector_type(4))) float floatx4;  // MFMA C/D frag

#define SEQ   4096
#define NBAT  8
#define DM    512
#define DINP  128
#define DFF   2048
#define NREAL 3000
#define CS    40              // ctx_mfma LDS stride (80B, 16B-aligned)

#define MFMA16(a,b,c) __builtin_amdgcn_mfma_f32_16x16x32_bf16((a),(b),(c),0,0,0)
#define BARRIER() asm volatile("s_barrier" ::: "memory")

// async global->LDS, 16B per lane, deposits at lds + lane*16
__device__ __forceinline__ void gload_lds16(const void* g, void* l) {
  auto* gp = reinterpret_cast<const __attribute__((address_space(1))) unsigned int*>(
      reinterpret_cast<uintptr_t>(g));
  auto* lp = reinterpret_cast<__attribute__((address_space(3))) unsigned int*>(
      reinterpret_cast<uintptr_t>(l));
  __builtin_amdgcn_global_load_lds(gp, lp, 16, 0, 0);
}

// opaque LDS 16B read: compiler sees no memory access -> no auto s_waitcnt.
// Caller MUST wait lgkmcnt + sched_barrier(0) before consuming (rule #18).
__device__ __forceinline__ short8 lds_read128(const bf16* p) {
  auto* lp = reinterpret_cast<const __attribute__((address_space(3))) bf16*>(
      reinterpret_cast<uintptr_t>(p));
  short8 r;
  asm volatile("ds_read_b128 %0, %1" : "=v"(r) : "v"(lp));
  return r;
}

// branch-free erf, Abramowitz-Stegun 7.1.26, |eps| <= 1.5e-7
__device__ __forceinline__ float fast_erff(float x) {
  float ax = fabsf(x);
  float t = __builtin_amdgcn_rcpf(fmaf(0.3275911f, ax, 1.f));
  float p = fmaf(fmaf(fmaf(fmaf(1.061405429f, t, -1.453152027f), t,
                           1.421413741f), t, -0.284496736f), t, 0.254829592f) * t;
  float r = 1.f - p * __expf(-ax * ax);
  return copysignf(r, x);
}

// tanh(x) = 1 - 2/(e^{2x}+1); saturates correctly at +-inf
__device__ __forceinline__ float fast_tanhf(float x) {
  float e = __expf(2.f * x);
  return 1.f - 2.f * __builtin_amdgcn_rcpf(e + 1.f);
}

// ---------------------------------------------------------------------------
__global__ __launch_bounds__(256) void beacon(float* __restrict__ out, long n) {
  long i = (long)blockIdx.x * 256 + threadIdx.x;
  if (i < n) out[i] = 10000.f;
}

// ---------------------------------------------------------------------------
// All 8 weight transposes in one launch. Wt[n][k] = n<N ? (bf16)W[k][n] : 0
// ---------------------------------------------------------------------------
__global__ __launch_bounds__(256) void transpose8(
    const float* __restrict__ W1, const float* __restrict__ Wq,
    const float* __restrict__ Wk, const float* __restrict__ Wv,
    const float* __restrict__ Wo, const float* __restrict__ Wf1,
    const float* __restrict__ Wf2, const float* __restrict__ W2,
    bf16* __restrict__ wt) {
  const int Ks[8]   = {128, 512, 512, 512, 512, 512, 2048, 512};
  const int Ns[8]   = {512, 512, 512, 512, 512, 2048, 512, 64};
  const int Nps[8]  = {512, 512, 512, 512, 512, 2048, 512, 128};
  const long Ofs[8] = {0L, 65536L, 327680L, 589824L, 851968L, 1114112L, 2162688L, 3211264L};
  int zi = blockIdx.z;
  int K = Ks[zi], N = Ns[zi], Npad = Nps[zi];
  int k0 = blockIdx.x * 64, n0 = blockIdx.y * 64;
  if (k0 >= K || n0 >= Npad) return;
  const float* W = zi == 0 ? W1 : zi == 1 ? Wq : zi == 2 ? Wk : zi == 3 ? Wv
                 : zi == 4 ? Wo : zi == 5 ? Wf1 : zi == 6 ? Wf2 : W2;
  bf16* Wt = wt + Ofs[zi];
  __shared__ float t[64][65];
  int r = threadIdx.x >> 2, c = (threadIdx.x & 3) * 16;
#pragma unroll
  for (int i = 0; i < 16; i++) {
    int n = n0 + c + i;
    t[r][c + i] = (n < N) ? W[(long)(k0 + r) * N + n] : 0.f;
  }
  __syncthreads();
#pragma unroll
  for (int i = 0; i < 16; i++)
    Wt[(long)(n0 + r) * K + k0 + c + i] = (bf16)t[c + i][r];
}

// ---------------------------------------------------------------------------
__device__ inline uint4 pack8(const float* p) {
  union { bf16 h[8]; uint4 u; } r;
  float4 a = *(const float4*)p;
  float4 b = *(const float4*)(p + 4);
  r.h[0] = (bf16)a.x; r.h[1] = (bf16)a.y; r.h[2] = (bf16)a.z; r.h[3] = (bf16)a.w;
  r.h[4] = (bf16)b.x; r.h[5] = (bf16)b.y; r.h[6] = (bf16)b.z; r.h[7] = (bf16)b.w;
  return r.u;
}

// ---------------------------------------------------------------------------
// gemm256: 256x256 MFMA GEMM. C[M x N] = epi(A @ Bt^T + bias).
// 512 threads = 8 waves (2M x 4N), per-wave C = 128x64. BK=64 per K-tile,
// double-buffered 128 KiB LDS. bf16 A only. M,N multiples of 256, K of 64.
// 8-phase m201-style: per phase {reads -> barrier -> lgkm0 -> 16 MFMA ->
// barrier}; tile t+1 staged in ONE 8-gload burst at ph0; single vmcnt(0)
// at ph3-end (loads then ~3 phases old). EPI: 1 bf16  2 fp32+=  4 gelu
// ---------------------------------------------------------------------------
__global__ __launch_bounds__(512, 2) void gemm256(
    const bf16* __restrict__ A, const bf16* __restrict__ Bt,
    const float* __restrict__ bias, float* __restrict__ Cf, bf16* __restrict__ Cb,
    int K, int lda, int ldb, int ldc, int EPI,
    long aBatch, long bBatch, int zdiv, long cOuter, long cInner) {
  // [buf][0=A,1=B][256 rows][64 cols] bf16 = 128 KiB
  __shared__ __align__(16) bf16 sm[2][2][256 * 64];
  const int tid = threadIdx.x;
  const int lane = tid & 63, wid = tid >> 6;

  // ---- T1: bijective XCD-chunk swizzle of flat block id ----
  const int nx = gridDim.x, ny = gridDim.y;
  const long nwg = (long)nx * ny * gridDim.z;
  const long fid = blockIdx.x + (long)nx * (blockIdx.y + (long)ny * blockIdx.z);
  const long cq = nwg >> 3, cr = nwg & 7;
  const long xcd = fid & 7, ofs = fid >> 3;
  const long swz = (xcd < cr ? xcd * (cq + 1) : cr * (cq + 1) + (xcd - cr) * cq) + ofs;
  const int bx = (int)(swz % nx);
  const int by = (int)((swz / nx) % ny);
  const int bz = (int)(swz / ((long)nx * ny));

  const bf16* Ab = A + (long)bz * aBatch;
  const bf16* Bb = Bt + (long)bz * bBatch;
  const long cOff = (long)(bz / zdiv) * cOuter + (long)(bz % zdiv) * cInner;
  const int row0 = by * 256;
  const int col0 = bx * 256;

  const int widm = wid >> 2, widn = wid & 3;      // 2 x 4 wave grid
  const int lr = lane & 15, lq4 = lane >> 4;
  const int sw = (lr & 7) << 4;                    // T2 read-side swizzle
  const int k0e = ((0 * 64 + lq4 * 16) ^ sw) >> 1; // kk=0 elem offset in row
  const int k1e = ((1 * 64 + lq4 * 16) ^ sw) >> 1; // kk=1

  // staging: per-wave 8-row slices, pre-swizzled global source (rule #21)
  const int lrow = lane >> 3;                      // row within slice
  const int lch = (lane & 7) ^ lrow;               // swizzled 16B chunk
  const bf16* pAbase = Ab + (long)(row0 + wid * 8 + lrow) * lda + lch * 8;
  const bf16* pBbase = Bb + (long)(col0 + wid * 8 + lrow) * ldb + lch * 8;
  const long a64 = (long)64 * lda, b64 = (long)64 * ldb;
  int kA = 0, kB = 0;

  floatx4 acc[8][4];
#pragma unroll
  for (int i = 0; i < 8; i++)
#pragma unroll
    for (int j = 0; j < 4; j++) acc[i][j] = {0.f, 0.f, 0.f, 0.f};

  auto stageA = [&](int buf, int h) {
    bf16* d = &sm[buf][0][(h * 128 + wid * 8) * 64];
    const bf16* g = pAbase + (long)(h * 2) * a64 + kA;
    gload_lds16(g, d);
    gload_lds16(g + a64, d + 64 * 64);
  };
  auto stageB = [&](int buf, int h) {
    bf16* d = &sm[buf][1][(h * 128 + wid * 8) * 64];
    const bf16* g = pBbase + (long)(h * 2) * b64 + kB;
    gload_lds16(g, d);
    gload_lds16(g + b64, d + 64 * 64);
  };
  auto stageAll = [&](int buf) {   // one burst: 8 gloads/wave, 3 phases of cover
    stageA(buf, 0); stageA(buf, 1); kA += 64;
    stageB(buf, 0); stageB(buf, 1); kB += 64;
  };

  short8 bfr[4][2], af[2][2];
  auto readB = [&](int buf) {
    const bf16* base = &sm[buf][1][0];
#pragma unroll
    for (int nt = 0; nt < 4; nt++) {
      int colB = widn * 64 + nt * 16 + lr;
      bfr[nt][0] = lds_read128(base + colB * 64 + k0e);
      bfr[nt][1] = lds_read128(base + colB * 64 + k1e);
    }
  };
  auto readA = [&](int buf, int q) {
    const bf16* base = &sm[buf][0][0];
#pragma unroll
    for (int m = 0; m < 2; m++) {
      int rowA = widm * 128 + q * 32 + m * 16 + lr;
      af[m][0] = lds_read128(base + rowA * 64 + k0e);
      af[m][1] = lds_read128(base + rowA * 64 + k1e);
    }
  };
  auto mmaq = [&](int q) {
    asm volatile("s_waitcnt lgkmcnt(0)" ::: "memory");
    __builtin_amdgcn_sched_barrier(0);          // rule #18: pin MFMA after wait
    __builtin_amdgcn_s_setprio(1);
#pragma unroll
    for (int m = 0; m < 2; m++)
#pragma unroll
      for (int nt = 0; nt < 4; nt++) {
        acc[q * 2 + m][nt] = MFMA16(af[m][0], bfr[nt][0], acc[q * 2 + m][nt]);
        acc[q * 2 + m][nt] = MFMA16(af[m][1], bfr[nt][1], acc[q * 2 + m][nt]);
      }
    __builtin_amdgcn_s_setprio(0);
  };

  const int T = K >> 6;
  // ---- prologue: tile0 (one-time full drain) ----
  stageAll(0);
  asm volatile("s_waitcnt vmcnt(0)" ::: "memory");
  BARRIER();

  for (int t = 0; t < T; t++) {
    const int cb = t & 1, nb = cb ^ 1;
    // ---- ph0: 12 reads + burst-stage t+1; barrier hides read latency ----
    readB(cb);
    readA(cb, 0);
    if (t + 1 < T) stageAll(nb);
    BARRIER();
    mmaq(0);
    BARRIER();
    // ---- ph1 ----
    readA(cb, 1);
    BARRIER();
    mmaq(1);
    BARRIER();
    // ---- ph2 ----
    readA(cb, 2);
    BARRIER();
    mmaq(2);
    BARRIER();
    // ---- ph3: vmcnt(0) waits on ~3-phase-old loads (nearly free) ----
    readA(cb, 3);
    BARRIER();
    mmaq(3);
    if (t + 1 < T) asm volatile("s_waitcnt vmcnt(0)" ::: "memory");
    BARRIER();
  }

  // ---- epilogue ----
  if (EPI == 2) {
    // fp32 += : already full-sector stores
#pragma unroll
    for (int nt = 0; nt < 4; nt++) {
      int c = col0 + widn * 64 + nt * 16 + lr;
      float bv = bias ? bias[c] : 0.f;
#pragma unroll
      for (int mi = 0; mi < 8; mi++) {
        long rb = row0 + widm * 128 + mi * 16 + lq4 * 4;
#pragma unroll
        for (int reg = 0; reg < 4; reg++) {
          float v = acc[mi][nt][reg] + bv;
          long idx = cOff + (rb + reg) * (long)ldc + c;
          Cf[idx] += v;
        }
      }
    }
  } else {
    // bf16 outputs (EPI 1/4): LDS-transposed coalesced stores.
    // Per-wave scratch 64 rows x 72-elem stride (4-row group = 144 dwords
    // === 16 mod 32 -> 2-way both sides = free); 2 passes of 64 rows;
    // dwordx4 global stores = 8 rows x 128B full lines per instruction.
    bf16* scr = ((bf16*)&sm[0][0][0]) + wid * (64 * 72);
    const int rr = lane >> 3, ccol = (lane & 7) * 8;
#pragma unroll
    for (int p = 0; p < 2; p++) {
#pragma unroll
      for (int nt = 0; nt < 4; nt++) {
        int c = col0 + widn * 64 + nt * 16 + lr;
        float bv = bias ? bias[c] : 0.f;
#pragma unroll
        for (int ml = 0; ml < 4; ml++) {
#pragma unroll
          for (int reg = 0; reg < 4; reg++) {
            float v = acc[p * 4 + ml][nt][reg] + bv;
            if (EPI == 4) v = 0.5f * v * (1.f + fast_erff(v * 0.70710678118654752f));
            scr[(ml * 16 + lq4 * 4 + reg) * 72 + nt * 16 + lr] = (bf16)v;
          }
        }
      }
#pragma unroll
      for (int it = 0; it < 8; it++) {
        int r = it * 8 + rr;
        uint4 v = *(const uint4*)&scr[r * 72 + ccol];
        long grow = row0 + widm * 128 + p * 64 + r;
        *(uint4*)&Cb[cOff + grow * (long)ldc + col0 + widn * 64 + ccol] = v;
      }
    }
  }
}

// ---------------------------------------------------------------------------
// Generic MFMA GEMM (legacy 128x128): used for xW1 (AMODE1), linear-out,
// final W2 (AMODE2). 256 threads (4 waves, 2x2), z-batched, XCD-swizzled.
// ---------------------------------------------------------------------------
__global__ __launch_bounds__(256) void gemm_bt(
    const void* __restrict__ Avoid, const bf16* __restrict__ Bt,
    const float* __restrict__ bias, float* __restrict__ Cf, bf16* __restrict__ Cb,
    int K, int lda, int ldb, int ldc, int EPI, int AMODE,
    long aBatch, long bBatch, int zdiv, long cOuter, long cInner) {
  __shared__ __align__(16) bf16 As0[128 * 32];
  __shared__ __align__(16) bf16 As1[128 * 32];
  __shared__ __align__(16) bf16 Bs0[128 * 32];
  __shared__ __align__(16) bf16 Bs1[128 * 32];
  const int tid = threadIdx.x;

  const int nx = gridDim.x, ny = gridDim.y;
  const long nwg = (long)nx * ny * gridDim.z;
  const long fid = blockIdx.x + (long)nx * (blockIdx.y + (long)ny * blockIdx.z);
  const long cq = nwg >> 3, cr = nwg & 7;
  const long xcd = fid & 7, ofs = fid >> 3;
  const long swz = (xcd < cr ? xcd * (cq + 1) : cr * (cq + 1) + (xcd - cr) * cq) + ofs;
  const int bx = (int)(swz % nx);
  const int by = (int)((swz / nx) % ny);
  const int bz = (int)(swz / ((long)nx * ny));

  Bt += (long)bz * bBatch;
  const long cOff = (long)(bz / zdiv) * cOuter + (long)(bz % zdiv) * cInner;
  const int row0 = by * 128;
  const int col0 = bx * 128;
  const int lane = tid & 63, wid = tid >> 6;
  const int wm = (wid & 1) * 64, wn = (wid >> 1) * 64;
  const int lr = lane & 15, lk = (lane >> 4) * 8;

  floatx4 acc[4][4];
#pragma unroll
  for (int i = 0; i < 4; i++)
#pragma unroll
    for (int j = 0; j < 4; j++) acc[i][j] = {0.f, 0.f, 0.f, 0.f};

  if (AMODE == 0) {
    const bf16* A = (const bf16*)Avoid + (long)bz * aBatch;
    const bf16* pAa = A + (long)(row0 + wid * 16 + (lane >> 2)) * lda + (lane & 3) * 8;
    const bf16* pBa = Bt + (long)(col0 + wid * 16 + (lane >> 2)) * ldb + (lane & 3) * 8;
    bf16* ldsA0 = &As0[wid * 16 * 32];
    bf16* ldsA1 = &As1[wid * 16 * 32];
    bf16* ldsB0 = &Bs0[wid * 16 * 32];
    bf16* ldsB1 = &Bs1[wid * 16 * 32];
    const long a64 = (long)64 * lda, b64 = (long)64 * ldb;

    auto stage = [&](bf16* dA, bf16* dB) {
      gload_lds16(pAa, dA);
      gload_lds16(pAa + a64, dA + 64 * 32);
      gload_lds16(pBa, dB);
      gload_lds16(pBa + b64, dB + 64 * 32);
      pAa += 32; pBa += 32;
    };
    auto compute = [&](const bf16* AS, const bf16* BS) {
      short8 af[4], bfr[4];
#pragma unroll
      for (int mt = 0; mt < 4; mt++) af[mt] = *(const short8*)(&AS[(wm + mt * 16 + lr) * 32 + lk]);
#pragma unroll
      for (int nt = 0; nt < 4; nt++) bfr[nt] = *(const short8*)(&BS[(wn + nt * 16 + lr) * 32 + lk]);
#pragma unroll
      for (int mt = 0; mt < 4; mt++)
#pragma unroll
        for (int nt = 0; nt < 4; nt++)
          acc[mt][nt] = MFMA16(af[mt], bfr[nt], acc[mt][nt]);
    };

    stage(ldsA0, ldsB0);
    __syncthreads();
    for (int k0 = 0; k0 < K; k0 += 64) {
      stage(ldsA1, ldsB1);
      compute(As0, Bs0);
      __syncthreads();
      if (k0 + 64 < K) stage(ldsA0, ldsB0);
      compute(As1, Bs1);
      __syncthreads();
    }
  } else {
    const float* Af = (const float*)Avoid;
    const int srow = tid >> 2;
    const int skcol = (tid & 3) * 8;
    const long r0 = row0 + srow, r1 = r0 + 64;
    const bf16* pB = Bt + (long)(col0 + srow) * ldb + skcol;
    const int ldsOff = srow * 32 + skcol;
    const float* pF0; const float* pF1;
    bool v0 = true, v1 = true;
    if (AMODE == 1) {
      int t0 = (int)(r0 & (SEQ - 1)), t1 = (int)(r1 & (SEQ - 1));
      v0 = t0 < NREAL; v1 = t1 < NREAL;
      if (!v0) t0 = 0;
      if (!v1) t1 = 0;
      pF0 = Af + ((r0 >> 12) * NREAL + t0) * DINP + skcol;
      pF1 = Af + ((r1 >> 12) * NREAL + t1) * DINP + skcol;
    } else {
      pF0 = Af + r0 * lda + skcol;
      pF1 = Af + r1 * lda + skcol;
    }
    for (int k0 = 0; k0 < K; k0 += 32) {
      uint4 b0 = *(const uint4*)(pB);
      uint4 b1 = *(const uint4*)(pB + (long)64 * ldb);
      pB += 32;
      uint4 a0 = {0, 0, 0, 0}, a1 = {0, 0, 0, 0};
      if (v0) a0 = pack8(pF0);
      if (v1) a1 = pack8(pF1);
      pF0 += 32; pF1 += 32;
      __syncthreads();
      *(uint4*)(&As0[ldsOff]) = a0;
      *(uint4*)(&As0[ldsOff + 64 * 32]) = a1;
      *(uint4*)(&Bs0[ldsOff]) = b0;
      *(uint4*)(&Bs0[ldsOff + 64 * 32]) = b1;
      __syncthreads();
      short8 af[4], bfr[4];
#pragma unroll
      for (int mt = 0; mt < 4; mt++) af[mt] = *(const short8*)(&As0[(wm + mt * 16 + lr) * 32 + lk]);
#pragma unroll
      for (int nt = 0; nt < 4; nt++) bfr[nt] = *(const short8*)(&Bs0[(wn + nt * 16 + lr) * 32 + lk]);
#pragma unroll
      for (int mt = 0; mt < 4; mt++)
#pragma unroll
        for (int nt = 0; nt < 4; nt++)
          acc[mt][nt] = MFMA16(af[mt], bfr[nt], acc[mt][nt]);
    }
  }

#pragma unroll
  for (int nt = 0; nt < 4; nt++) {
    int c = col0 + wn + nt * 16 + lr;
    float bv = 0.f;
    if (bias) {
      if (EPI == 5) { if (c < 64) bv = bias[c]; }
      else bv = bias[c];
    }
#pragma unroll
    for (int mt = 0; mt < 4; mt++) {
      long rb = row0 + wm + mt * 16 + (lane >> 4) * 4;
#pragma unroll
      for (int reg = 0; reg < 4; reg++) {
        float v = acc[mt][nt][reg] + bv;
        long ri = rb + reg;
        long idx = cOff + ri * (long)ldc + c;
        if (EPI == 0) Cf[idx] = fast_tanhf(v);
        else if (EPI == 1) Cb[idx] = (bf16)v;
        else if (EPI == 2) Cf[idx] += v;
        else if (EPI == 4) { float g = 0.5f * v * (1.f + fast_erff(v * 0.70710678118654752f)); Cb[idx] = (bf16)g; }
        else if (EPI == 5) {
          int bb = (int)(ri >> 12); int tt = (int)(ri & (SEQ - 1));
          if (tt < NREAL && c < 64) Cf[((long)bb * NREAL + tt) * 64 + c] = v;
        }
      }
    }
  }
}

// ---------------------------------------------------------------------------
// LayerNorm over 512 fp32 -> bf16. One wave per row, 4 rows per block.
// ---------------------------------------------------------------------------
__global__ __launch_bounds__(256) void ln_kernel(const float* __restrict__ h,
                                                 const float* __restrict__ g,
                                                 const float* __restrict__ bta,
                                                 bf16* __restrict__ out) {
  int wid = threadIdx.x >> 6, lane = threadIdx.x & 63;
  long row = (long)blockIdx.x * 4 + wid;
  const float* src = h + row * DM + lane * 8;
  float4 a = *(const float4*)(src);
  float4 b = *(const float4*)(src + 4);
  float x[8] = {a.x, a.y, a.z, a.w, b.x, b.y, b.z, b.w};
  float s = 0.f, sq = 0.f;
#pragma unroll
  for (int i = 0; i < 8; i++) { s += x[i]; sq += x[i] * x[i]; }
#pragma unroll
  for (int m = 32; m >= 1; m >>= 1) { s += __shfl_xor(s, m, 64); sq += __shfl_xor(sq, m, 64); }
  float mu = s * (1.f / DM);
  float var = sq * (1.f / DM) - mu * mu;
  float rstd = rsqrtf(var + 1e-5f);
  const float* gp = g + lane * 8;
  const float* bp = bta + lane * 8;
  bf16* dst = out + row * DM + lane * 8;
#pragma unroll
  for (int i = 0; i < 8; i++)
    dst[i] = (bf16)((x[i] - mu) * rstd * gp[i] + bp[i]);
}

// ---------------------------------------------------------------------------
// Local attention, head 0. Grid (2 halves, 32 windows, GB batches).
// ---------------------------------------------------------------------------
__global__ __launch_bounds__(256) void local_attn(const bf16* __restrict__ q,
                                                  const bf16* __restrict__ k,
                                                  const bf16* __restrict__ v,
                                                  bf16* __restrict__ att) {
  int half = blockIdx.x, w = blockIdx.y, b = blockIdx.z;
  int tid = threadIdx.x, wid = tid >> 6, lane = tid & 63;
  int lr = lane & 15, lq4 = lane >> 4;
  __shared__ __align__(16) bf16 Ks[32 * 128];   // [j][d]
  __shared__ __align__(16) bf16 Vts[128 * 32];  // [d][j]
  __shared__ __align__(16) bf16 Ps[4][16 * 32]; // per-wave P scratch

  int t0 = w * 128 + half * 64 + wid * 16;
  long qbase = ((long)b * SEQ + t0 + lr) * DM;
  short8 qf[4];
#pragma unroll
  for (int ks = 0; ks < 4; ks++) qf[ks] = *(const short8*)(q + qbase + ks * 32 + lq4 * 8);

  floatx4 Oacc[8];
#pragma unroll
  for (int i = 0; i < 8; i++) Oacc[i] = {0.f, 0.f, 0.f, 0.f};
  float rs[4] = {0.f, 0.f, 0.f, 0.f};

  int keystart = w * 128 - 128;
  for (int ch = 0; ch < 12; ch++) {
    int kb = keystart + ch * 32;
    if (kb < 0 || kb >= SEQ) continue;  // uniform per block
    {
      int j = tid >> 3, d = (tid & 7) * 16;
      const bf16* ksrc = k + ((long)b * SEQ + kb + j) * DM + d;
      *(uint4*)(&Ks[j * 128 + d]) = *(const uint4*)(ksrc);
      *(uint4*)(&Ks[j * 128 + d + 8]) = *(const uint4*)(ksrc + 8);
      const bf16* vsrc = v + ((long)b * SEQ + kb + j) * DM + d;
#pragma unroll
      for (int e = 0; e < 16; e++) Vts[(d + e) * 32 + j] = vsrc[e];
    }
    __syncthreads();
    floatx4 s0 = {0.f, 0.f, 0.f, 0.f}, s1 = {0.f, 0.f, 0.f, 0.f};
#pragma unroll
    for (int ks = 0; ks < 4; ks++) {
      short8 kf0 = *(const short8*)(&Ks[(0 + lr) * 128 + ks * 32 + lq4 * 8]);
      short8 kf1 = *(const short8*)(&Ks[(16 + lr) * 128 + ks * 32 + lq4 * 8]);
      s0 = MFMA16(qf[ks], kf0, s0);
      s1 = MFMA16(qf[ks], kf1, s1);
    }
#pragma unroll
    for (int reg = 0; reg < 4; reg++) {
      float e0 = __expf(s0[reg] * 0.08838834764831845f);
      float e1 = __expf(s1[reg] * 0.08838834764831845f);
      rs[reg] += e0 + e1;
      Ps[wid][(lq4 * 4 + reg) * 32 + lr] = (bf16)e0;
      Ps[wid][(lq4 * 4 + reg) * 32 + 16 + lr] = (bf16)e1;
    }
    __syncthreads();
    short8 pf = *(const short8*)(&Ps[wid][lr * 32 + lq4 * 8]);
#pragma unroll
    for (int nt = 0; nt < 8; nt++) {
      short8 vf = *(const short8*)(&Vts[(nt * 16 + lr) * 32 + lq4 * 8]);
      Oacc[nt] = MFMA16(pf, vf, Oacc[nt]);
    }
    __syncthreads();
  }
#pragma unroll
  for (int m = 1; m < 16; m <<= 1)
#pragma unroll
    for (int reg = 0; reg < 4; reg++) rs[reg] += __shfl_xor(rs[reg], m, 64);
  long obase = ((long)b * SEQ + t0 + lq4 * 4) * DM;
#pragma unroll
  for (int nt = 0; nt < 8; nt++)
#pragma unroll
    for (int reg = 0; reg < 4; reg++)
      att[obase + (long)reg * DM + nt * 16 + lr] = (bf16)(Oacc[nt][reg] / rs[reg]);
}

// ---------------------------------------------------------------------------
// Linear-attn q-softmax: qp[z][t][128] = softmax(q_head)*d^-0.5, z=lb*3+h2
// ---------------------------------------------------------------------------
__global__ __launch_bounds__(256) void qp_softmax(const bf16* __restrict__ q, bf16* __restrict__ qp) {
  int wid = threadIdx.x >> 6, lane = threadIdx.x & 63;
  long task = (long)blockIdx.x * 4 + wid;
  int tt = (int)(task & (SEQ - 1));
  int z6 = (int)(task >> 12);
  int lb = z6 / 3, h2 = z6 % 3;
  const bf16* src = q + ((long)lb * SEQ + tt) * DM + (h2 + 1) * 128 + lane * 2;
  float x0 = (float)src[0], x1 = (float)src[1];
  float m = fmaxf(x0, x1);
#pragma unroll
  for (int s = 32; s >= 1; s >>= 1) m = fmaxf(m, __shfl_xor(m, s, 64));
  float e0 = __expf(x0 - m), e1 = __expf(x1 - m);
  float sm = e0 + e1;
#pragma unroll
  for (int s = 32; s >= 1; s >>= 1) sm += __shfl_xor(sm, s, 64);
  float inv = 0.08838834764831845f / sm;
  bf16* dst = qp + task * 128 + lane * 2;
  dst[0] = (bf16)(e0 * inv);
  dst[1] = (bf16)(e1 * inv);
}

// ---------------------------------------------------------------------------
// k column stats, phase 1: per-(z, 128-row chunk) column max and exp-sum.
// ---------------------------------------------------------------------------
__global__ __launch_bounds__(128) void kstats_part(const bf16* __restrict__ k,
                                                   float* __restrict__ part, int lOff) {
  int chunk = blockIdx.x, z = blockIdx.y;
  int lb = z / 3, h2 = z % 3, ch = (h2 + 1) * 128;
  int d = threadIdx.x;
  const bf16* base = k + ((long)lb * SEQ + chunk * 128) * DM + ch + d;
  float m = -1e30f;
#pragma unroll 4
  for (int t = 0; t < 128; t++) m = fmaxf(m, (float)base[(long)t * DM]);
  float l = 0.f;
#pragma unroll 4
  for (int t = 0; t < 128; t++) l += __expf((float)base[(long)t * DM] - m);
  int idx = (z * 32 + chunk) * 128 + d;
  part[idx] = m;
  part[lOff + idx] = l;
}

// phase 2: combine 32 chunk stats -> kml[z*256+d]=M, +128=L
__global__ __launch_bounds__(128) void kstats_comb(const float* __restrict__ part,
                                                   float* __restrict__ kml, int lOff) {
  int z = blockIdx.x, d = threadIdx.x;
  float M = -1e30f;
#pragma unroll 4
  for (int c = 0; c < 32; c++) M = fmaxf(M, part[(z * 32 + c) * 128 + d]);
  float L = 0.f;
#pragma unroll 4
  for (int c = 0; c < 32; c++) {
    int i = (z * 32 + c) * 128 + d;
    L += part[lOff + i] * __expf(part[i] - M);
  }
  kml[z * 256 + d] = M;
  kml[z * 256 + 128 + d] = L;
}

// ---------------------------------------------------------------------------
// ctx via MFMA: part[z][chunk][e*128+d] = sum_{t in 512-chunk} v[t][e]*k'[t][d]
// ---------------------------------------------------------------------------
__global__ __launch_bounds__(256) void ctx_mfma(const bf16* __restrict__ k,
                                                const bf16* __restrict__ v,
                                                const float* __restrict__ kml,
                                                float* __restrict__ part) {
  int chunk = blockIdx.x, z = blockIdx.y;
  int lb = z / 3, h2 = z % 3, ch = (h2 + 1) * 128;
  int tid = threadIdx.x, lane = tid & 63, wid = tid >> 6;
  const int wm = (wid & 1) * 64, wn = (wid >> 1) * 64;
  const int lr = lane & 15, lk = (lane >> 4) * 8;
  __shared__ float ml2[128];
  __shared__ __align__(16) bf16 Vt[128 * CS];
  __shared__ __align__(16) bf16 Kt[128 * CS];
  if (tid < 128)
    ml2[tid] = kml[z * 256 + tid] + logf(kml[z * 256 + 128 + tid]);

  int j = tid >> 3, d0 = (tid & 7) * 16;
  const bf16* vsrc = v + ((long)lb * SEQ + chunk * 512 + j) * DM + ch + d0;
  const bf16* ksrc = k + ((long)lb * SEQ + chunk * 512 + j) * DM + ch + d0;

  floatx4 acc[4][4];
#pragma unroll
  for (int i = 0; i < 4; i++)
#pragma unroll
    for (int jj = 0; jj < 4; jj++) acc[i][jj] = {0.f, 0.f, 0.f, 0.f};

  for (int s = 0; s < 16; s++) {
    union { bf16 h[16]; uint4 u[2]; } va, ka;
    va.u[0] = *(const uint4*)(vsrc); va.u[1] = *(const uint4*)(vsrc + 8);
    ka.u[0] = *(const uint4*)(ksrc); ka.u[1] = *(const uint4*)(ksrc + 8);
    vsrc += (long)32 * DM; ksrc += (long)32 * DM;
    __syncthreads();
#pragma unroll
    for (int e = 0; e < 16; e++) {
      Vt[(d0 + e) * CS + j] = va.h[e];
      Kt[(d0 + e) * CS + j] = (bf16)__expf((float)ka.h[e] - ml2[d0 + e]);
    }
    __syncthreads();
    short8 af[4], bfr[4];
#pragma unroll
    for (int mt = 0; mt < 4; mt++) af[mt] = *(const short8*)(&Vt[(wm + mt * 16 + lr) * CS + lk]);
#pragma unroll
    for (int nt = 0; nt < 4; nt++) bfr[nt] = *(const short8*)(&Kt[(wn + nt * 16 + lr) * CS + lk]);
#pragma unroll
    for (int mt = 0; mt < 4; mt++)
#pragma unroll
      for (int nt = 0; nt < 4; nt++)
        acc[mt][nt] = MFMA16(af[mt], bfr[nt], acc[mt][nt]);
  }

  float* dst = part + ((long)z * 8 + chunk) * 16384;
#pragma unroll
  for (int nt = 0; nt < 4; nt++) {
    int c = wn + nt * 16 + lr;
#pragma unroll
    for (int mt = 0; mt < 4; mt++) {
      int rb = wm + mt * 16 + (lane >> 4) * 4;
#pragma unroll
      for (int reg = 0; reg < 4; reg++)
        dst[(rb + reg) * 128 + c] = acc[mt][nt][reg];
    }
  }
}

__global__ __launch_bounds__(256) void ctx_reduce(const float* __restrict__ part, bf16* __restrict__ ctxT) {
  long i = (long)blockIdx.x * 256 + threadIdx.x;
  int z = (int)(i >> 14);
  int off = (int)(i & 16383);
  float s = 0.f;
#pragma unroll
  for (int c = 0; c < 8; c++) s += part[(((long)z * 8 + c) << 14) + off];
  ctxT[i] = (bf16)s;
}

// ---------------------------------------------------------------------------
extern "C" void kernel_launch(void* const* d_in, const int* in_sizes, int n_in,
                              void* d_out, int out_size, void* d_ws, size_t ws_size,
                              hipStream_t stream) {
  float* outp = (float*)d_out;

  // ---- adaptive arena: pick largest GB in {8,4,2} that fits ws_size ----
  long offH = 0;
  int GB = 0;
  long offLNG, offQ, offK, offV, offATT, offCTXP, offCTXT, offKML, offWT, need;
  for (int gb = 8; gb >= 2; gb >>= 1) {
    long sLN = (long)gb * 4194304;
    offLNG = 67108864L;
    offQ   = offLNG + sLN;
    offK   = offQ + sLN;
    offV   = offK + sLN;
    offATT = offV + sLN;
    offCTXP= offATT + sLN;
    offCTXT= offCTXP + (long)gb * 1572864;
    offKML = offCTXT + (long)gb * 98304;
    offWT  = offKML + (long)gb * 3072;
    need   = offWT + 6553600L;
    if ((size_t)need <= ws_size) { GB = gb; break; }
  }
  if (GB == 0) {
    beacon<<<(out_size + 255) / 256, 256, 0, stream>>>(outp, out_size);
    return;
  }
  const int NG = NBAT / GB;            // groups
  const long GR = (long)GB * SEQ;      // rows per group
  const int NZ = GB * 3;               // linear-attn (batch,head) pairs per group

  const float* x   = (const float*)d_in[0];
  const float* W1  = (const float*)d_in[1];
  const float* b1  = (const float*)d_in[2];
  const float* g1  = (const float*)d_in[3];
  const float* be1 = (const float*)d_in[4];
  const float* Wq  = (const float*)d_in[5];
  const float* Wk  = (const float*)d_in[6];
  const float* Wv  = (const float*)d_in[7];
  const float* Wo  = (const float*)d_in[8];
  const float* bo  = (const float*)d_in[9];
  const float* g2  = (const float*)d_in[10];
  const float* be2 = (const float*)d_in[11];
  const float* Wf1 = (const float*)d_in[12];
  const float* bf1 = (const float*)d_in[13];
  const float* Wf2 = (const float*)d_in[14];
  const float* bf2 = (const float*)d_in[15];
  const float* W2  = (const float*)d_in[16];
  const float* b2  = (const float*)d_in[17];

  char* ws = (char*)d_ws;
  float* h   = (float*)(ws + offH);
  bf16* lnG  = (bf16*)(ws + offLNG);
  bf16* qp   = (bf16*)(ws + offLNG);   // overlays lnG (lnG dead after QKV; qp dead in FFN)
  bf16* qb   = (bf16*)(ws + offQ);
  bf16* kb   = (bf16*)(ws + offK);
  bf16* vb   = (bf16*)(ws + offV);
  bf16* attb = (bf16*)(ws + offATT);
  bf16* ff1g = (bf16*)(ws + offQ);     // overlays q..attn (dead in FFN phase)
  float* ctxp= (float*)(ws + offCTXP);
  bf16* ctxT = (bf16*)(ws + offCTXT);
  float* kml = (float*)(ws + offKML);
  bf16* wt   = (bf16*)(ws + offWT);
  bf16* wqt  = wt + 65536;
  bf16* wot  = wt + 851968;
  bf16* wf1t = wt + 1114112;
  bf16* wf2t = wt + 2162688;
  bf16* w2t  = wt + 3211264;
  const int lOff = NZ * 32 * 128;      // kstats l-plane offset within ctxp

  // ---- all weight transposes (fp32 -> bf16, [Npad][K] K-contiguous) ----
  transpose8<<<dim3(32, 32, 8), 256, 0, stream>>>(W1, Wq, Wk, Wv, Wo, Wf1, Wf2, W2, wt);

  // ---- h = tanh(xpad @ W1 + b1) fp32; pad rows handled in A staging ----
  gemm_bt<<<dim3(4, 256, 1), 256, 0, stream>>>(x, wt, b1, h, nullptr,
      DINP, DINP, DINP, DM, 0, 1, 0, 0, 1, 0, 0);

  // ---- attention, NG groups of GB batches ----
  for (int g = 0; g < NG; g++) {
    float* hg = h + (long)g * GR * DM;
    ln_kernel<<<(int)(GR / 4), 256, 0, stream>>>(hg, g1, be1, lnG);
    // Q,K,V in one z=3 batched launch (outputs land in qb,kb,vb = contiguous)
    gemm256<<<dim3(2, (int)(GR / 256), 3), 512, 0, stream>>>(lnG, wqt, nullptr, nullptr, qb,
        DM, DM, DM, DM, 1,
        0L, 262144L, 3, 0L, GR * DM);

    local_attn<<<dim3(2, 32, GB), 256, 0, stream>>>(qb, kb, vb, attb);

    qp_softmax<<<NZ * 1024, 256, 0, stream>>>(qb, qp);
    kstats_part<<<dim3(32, NZ), 128, 0, stream>>>(kb, ctxp, lOff);
    kstats_comb<<<NZ, 128, 0, stream>>>(ctxp, kml, lOff);
    ctx_mfma<<<dim3(8, NZ), 256, 0, stream>>>(kb, vb, kml, ctxp);
    ctx_reduce<<<NZ * 64, 256, 0, stream>>>(ctxp, ctxT);
    gemm_bt<<<dim3(1, 32, NZ), 256, 0, stream>>>(qp, ctxT, nullptr, nullptr, attb + 128,
        128, 128, 128, DM, 1, 0,
        (long)SEQ * 128, 16384L, 3, (long)SEQ * DM, 128L);

    // h += attn @ Wo + bo : 256-tile, block-owned +=
    gemm256<<<dim3(2, (int)(GR / 256), 1), 512, 0, stream>>>(attb, wot, bo, hg, nullptr,
        DM, DM, DM, DM, 2, 0, 0, 1, 0, 0);
  }

  // ---- FFN, NG groups ----
  for (int g = 0; g < NG; g++) {
    float* hg = h + (long)g * GR * DM;
    ln_kernel<<<(int)(GR / 4), 256, 0, stream>>>(hg, g2, be2, lnG);
    gemm256<<<dim3(8, (int)(GR / 256), 1), 512, 0, stream>>>(lnG, wf1t, bf1, nullptr, ff1g,
        DM, DM, DM, DFF, 4, 0, 0, 1, 0, 0);
    // h += gelu(ff1) @ Wf2 + bf2 : 256-tile, block-owned +=
    gemm256<<<dim3(2, (int)(GR / 256), 1), 512, 0, stream>>>(ff1g, wf2t, bf2, hg, nullptr,
        DFF, DFF, DFF, DM, 2, 0, 0, 1, 0, 0);
  }

  // ---- out = (h @ W2 + b2)[:, :3000, :] -> d_out fp32 (h staged as bf16) ----
  gemm_bt<<<dim3(1, 256, 1), 256, 0, stream>>>(h, w2t, b2, outp, nullptr,
      DM, DM, DM, 64, 5, 2, 0, 0, 1, 0, 0);
}

// Round 9
// 650.205 us; speedup vs baseline: 1.0465x; 1.0465x over previous
//
#include <hip/hip_runtime.h>
#include <hip/hip_bf16.h>
#include <math.h>

// ---------------------------------------------------------------------------
// Linear_Transformer on MI355X (gfx950). fp32 I/O, bf16 MFMA internals,
// fp32 residual stream.
// Round 19: gemm256 gets TRUE counted-vmcnt (T4) via asymmetric buffering:
// A double-buffered (64KB) + B TRIPLE-buffered rotation (96KB) = 160KB LDS
// (AITER precedent: 160KB/block works on gfx950). Per tile: stage A(t+1) at
// p0, B(t+2) at p2; tile-end wait = vmcnt(4) -> B(t+2)'s 4 loads stay in
// flight ACROSS the barrier (queue never drains; the m218-measured +38-73%
// lever vs drain0, which all R4-R8 variants were). One barrier/tile
// (hazard ledger: A-nb stage@p0 vs nb reads: t-1 reads lgkm-drained by
// mmaq(3)+tile-end barrier; B-rot buffer (t+2)%3 stage@p2 vs last reads at
// t-1 p0: >=1 barrier between; reads of t's data vs their stages: vmcnt
// ladder + barrier. Intra-tile cross-wave: stages target non-read buffers).
// vmcnt ladder: steady vmcnt(4); t+2==T -> vmcnt(0); t=T-1 none. Prologue:
// A(0),B(0),B(1) then vmcnt(4) (B(1) flies). Epilogue scratch reuses sm[0..]
// after the final tile barrier. All other kernels unchanged.
// ---------------------------------------------------------------------------

typedef __hip_bfloat16 bf16;
typedef __attribute__((ext_vector_type(8))) short short8;   // 8 bf16 (MFMA A/B frag)
typedef __attribute__((ext_vector_type(4))) float floatx4;  // MFMA C/D frag

#define SEQ   4096
#define NBAT  8
#define DM    512
#define DINP  128
#define DFF   2048
#define NREAL 3000
#define CS    40              // ctx_mfma LDS stride (80B, 16B-aligned)

#define MFMA16(a,b,c) __builtin_amdgcn_mfma_f32_16x16x32_bf16((a),(b),(c),0,0,0)
#define BARRIER() asm volatile("s_barrier" ::: "memory")

// async global->LDS, 16B per lane, deposits at lds + lane*16
__device__ __forceinline__ void gload_lds16(const void* g, void* l) {
  auto* gp = reinterpret_cast<const __attribute__((address_space(1))) unsigned int*>(
      reinterpret_cast<uintptr_t>(g));
  auto* lp = reinterpret_cast<__attribute__((address_space(3))) unsigned int*>(
      reinterpret_cast<uintptr_t>(l));
  __builtin_amdgcn_global_load_lds(gp, lp, 16, 0, 0);
}

// opaque LDS 16B read: compiler sees no memory access -> no auto s_waitcnt.
// Caller MUST wait lgkmcnt + sched_barrier(0) before consuming (rule #18).
__device__ __forceinline__ short8 lds_read128(const bf16* p) {
  auto* lp = reinterpret_cast<const __attribute__((address_space(3))) bf16*>(
      reinterpret_cast<uintptr_t>(p));
  short8 r;
  asm volatile("ds_read_b128 %0, %1" : "=v"(r) : "v"(lp));
  return r;
}

// branch-free erf, Abramowitz-Stegun 7.1.26, |eps| <= 1.5e-7
__device__ __forceinline__ float fast_erff(float x) {
  float ax = fabsf(x);
  float t = __builtin_amdgcn_rcpf(fmaf(0.3275911f, ax, 1.f));
  float p = fmaf(fmaf(fmaf(fmaf(1.061405429f, t, -1.453152027f), t,
                           1.421413741f), t, -0.284496736f), t, 0.254829592f) * t;
  float r = 1.f - p * __expf(-ax * ax);
  return copysignf(r, x);
}

// tanh(x) = 1 - 2/(e^{2x}+1); saturates correctly at +-inf
__device__ __forceinline__ float fast_tanhf(float x) {
  float e = __expf(2.f * x);
  return 1.f - 2.f * __builtin_amdgcn_rcpf(e + 1.f);
}

// ---------------------------------------------------------------------------
__global__ __launch_bounds__(256) void beacon(float* __restrict__ out, long n) {
  long i = (long)blockIdx.x * 256 + threadIdx.x;
  if (i < n) out[i] = 10000.f;
}

// ---------------------------------------------------------------------------
// All 8 weight transposes in one launch. Wt[n][k] = n<N ? (bf16)W[k][n] : 0
// ---------------------------------------------------------------------------
__global__ __launch_bounds__(256) void transpose8(
    const float* __restrict__ W1, const float* __restrict__ Wq,
    const float* __restrict__ Wk, const float* __restrict__ Wv,
    const float* __restrict__ Wo, const float* __restrict__ Wf1,
    const float* __restrict__ Wf2, const float* __restrict__ W2,
    bf16* __restrict__ wt) {
  const int Ks[8]   = {128, 512, 512, 512, 512, 512, 2048, 512};
  const int Ns[8]   = {512, 512, 512, 512, 512, 2048, 512, 64};
  const int Nps[8]  = {512, 512, 512, 512, 512, 2048, 512, 128};
  const long Ofs[8] = {0L, 65536L, 327680L, 589824L, 851968L, 1114112L, 2162688L, 3211264L};
  int zi = blockIdx.z;
  int K = Ks[zi], N = Ns[zi], Npad = Nps[zi];
  int k0 = blockIdx.x * 64, n0 = blockIdx.y * 64;
  if (k0 >= K || n0 >= Npad) return;
  const float* W = zi == 0 ? W1 : zi == 1 ? Wq : zi == 2 ? Wk : zi == 3 ? Wv
                 : zi == 4 ? Wo : zi == 5 ? Wf1 : zi == 6 ? Wf2 : W2;
  bf16* Wt = wt + Ofs[zi];
  __shared__ float t[64][65];
  int r = threadIdx.x >> 2, c = (threadIdx.x & 3) * 16;
#pragma unroll
  for (int i = 0; i < 16; i++) {
    int n = n0 + c + i;
    t[r][c + i] = (n < N) ? W[(long)(k0 + r) * N + n] : 0.f;
  }
  __syncthreads();
#pragma unroll
  for (int i = 0; i < 16; i++)
    Wt[(long)(n0 + r) * K + k0 + c + i] = (bf16)t[c + i][r];
}

// ---------------------------------------------------------------------------
__device__ inline uint4 pack8(const float* p) {
  union { bf16 h[8]; uint4 u; } r;
  float4 a = *(const float4*)p;
  float4 b = *(const float4*)(p + 4);
  r.h[0] = (bf16)a.x; r.h[1] = (bf16)a.y; r.h[2] = (bf16)a.z; r.h[3] = (bf16)a.w;
  r.h[4] = (bf16)b.x; r.h[5] = (bf16)b.y; r.h[6] = (bf16)b.z; r.h[7] = (bf16)b.w;
  return r.u;
}

// ---------------------------------------------------------------------------
// gemm256: 256x256 MFMA GEMM. C[M x N] = epi(A @ Bt^T + bias).
// 512 threads = 8 waves (2M x 4N), per-wave C = 128x64. BK=64 per K-tile.
// A: 2-buffer (64KB); B: 3-buffer rotation (96KB); 160KB LDS total.
// Counted vmcnt(4) per tile keeps B(t+2)'s loads in flight across the
// single tile-end barrier. EPI: 1 bf16  2 fp32+=  4 gelu
// ---------------------------------------------------------------------------
__global__ __launch_bounds__(512, 2) void gemm256(
    const bf16* __restrict__ A, const bf16* __restrict__ Bt,
    const float* __restrict__ bias, float* __restrict__ Cf, bf16* __restrict__ Cb,
    int K, int lda, int ldb, int ldc, int EPI,
    long aBatch, long bBatch, int zdiv, long cOuter, long cInner) {
  // [A0|A1|B0|B1|B2], each 256 rows x 64 cols bf16 (32 KiB) = 160 KiB
  __shared__ __align__(16) bf16 sm[5 * 256 * 64];
  bf16* const smB = sm + 2 * 16384;
  const int tid = threadIdx.x;
  const int lane = tid & 63, wid = tid >> 6;

  // ---- T1: bijective XCD-chunk swizzle of flat block id ----
  const int nx = gridDim.x, ny = gridDim.y;
  const long nwg = (long)nx * ny * gridDim.z;
  const long fid = blockIdx.x + (long)nx * (blockIdx.y + (long)ny * blockIdx.z);
  const long cq = nwg >> 3, cr = nwg & 7;
  const long xcd = fid & 7, ofs = fid >> 3;
  const long swz = (xcd < cr ? xcd * (cq + 1) : cr * (cq + 1) + (xcd - cr) * cq) + ofs;
  const int bx = (int)(swz % nx);
  const int by = (int)((swz / nx) % ny);
  const int bz = (int)(swz / ((long)nx * ny));

  const bf16* Ab = A + (long)bz * aBatch;
  const bf16* Bb = Bt + (long)bz * bBatch;
  const long cOff = (long)(bz / zdiv) * cOuter + (long)(bz % zdiv) * cInner;
  const int row0 = by * 256;
  const int col0 = bx * 256;

  const int widm = wid >> 2, widn = wid & 3;      // 2 x 4 wave grid
  const int lr = lane & 15, lq4 = lane >> 4;
  const int sw = (lr & 7) << 4;                    // T2 read-side swizzle
  const int k0e = ((0 * 64 + lq4 * 16) ^ sw) >> 1; // kk=0 elem offset in row
  const int k1e = ((1 * 64 + lq4 * 16) ^ sw) >> 1; // kk=1

  // staging: per-wave 8-row slices, pre-swizzled global source (rule #21)
  const int lrow = lane >> 3;                      // row within slice
  const int lch = (lane & 7) ^ lrow;               // swizzled 16B chunk
  const bf16* pAbase = Ab + (long)(row0 + wid * 8 + lrow) * lda + lch * 8;
  const bf16* pBbase = Bb + (long)(col0 + wid * 8 + lrow) * ldb + lch * 8;
  const long a64 = (long)64 * lda, b64 = (long)64 * ldb;
  int kA = 0, kB = 0;

  floatx4 acc[8][4];
#pragma unroll
  for (int i = 0; i < 8; i++)
#pragma unroll
    for (int j = 0; j < 4; j++) acc[i][j] = {0.f, 0.f, 0.f, 0.f};

  // stage full A tile (4 gloads/wave, issued as one FIFO group)
  auto stageA4 = [&](int buf) {
    bf16* base = sm + buf * 16384;
#pragma unroll
    for (int h = 0; h < 2; h++) {
      bf16* d = base + (h * 128 + wid * 8) * 64;
      const bf16* g = pAbase + (long)(h * 2) * a64 + kA;
      gload_lds16(g, d);
      gload_lds16(g + a64, d + 64 * 64);
    }
    kA += 64;
  };
  // stage full B tile into rotation slot (4 gloads/wave)
  auto stageB4 = [&](int slot) {
    bf16* base = smB + slot * 16384;
#pragma unroll
    for (int h = 0; h < 2; h++) {
      bf16* d = base + (h * 128 + wid * 8) * 64;
      const bf16* g = pBbase + (long)(h * 2) * b64 + kB;
      gload_lds16(g, d);
      gload_lds16(g + b64, d + 64 * 64);
    }
    kB += 64;
  };

  short8 bfr[4][2], af[2][2];
  auto readB = [&](int slot) {
    const bf16* base = smB + slot * 16384;
#pragma unroll
    for (int nt = 0; nt < 4; nt++) {
      int colB = widn * 64 + nt * 16 + lr;
      bfr[nt][0] = lds_read128(base + colB * 64 + k0e);
      bfr[nt][1] = lds_read128(base + colB * 64 + k1e);
    }
  };
  auto readA = [&](int buf, int q) {
    const bf16* base = sm + buf * 16384;
#pragma unroll
    for (int m = 0; m < 2; m++) {
      int rowA = widm * 128 + q * 32 + m * 16 + lr;
      af[m][0] = lds_read128(base + rowA * 64 + k0e);
      af[m][1] = lds_read128(base + rowA * 64 + k1e);
    }
  };
  auto mmaq = [&](int q) {
    asm volatile("s_waitcnt lgkmcnt(0)" ::: "memory");
    __builtin_amdgcn_sched_barrier(0);          // rule #18: pin MFMA after wait
    __builtin_amdgcn_s_setprio(1);
#pragma unroll
    for (int m = 0; m < 2; m++)
#pragma unroll
      for (int nt = 0; nt < 4; nt++) {
        acc[q * 2 + m][nt] = MFMA16(af[m][0], bfr[nt][0], acc[q * 2 + m][nt]);
        acc[q * 2 + m][nt] = MFMA16(af[m][1], bfr[nt][1], acc[q * 2 + m][nt]);
      }
    __builtin_amdgcn_s_setprio(0);
  };

  const int T = K >> 6;
  // ---- prologue: A(0), B(0), B(1); newest 4 (=B(1)) stay in flight ----
  stageA4(0);
  stageB4(0);
  stageB4(1);
  asm volatile("s_waitcnt vmcnt(4)" ::: "memory");
  BARRIER();

  int bsel = 0;                        // = t % 3
  for (int t = 0; t < T; t++) {
    const int cb = t & 1, nb = cb ^ 1;
    // p0: tile reads (B all + A q0); stage A(t+1) -> nb
    readB(bsel);
    readA(cb, 0);
    if (t + 1 < T) stageA4(nb);
    mmaq(0);
    // p1..p3: free-running (per-wave lgkm waits only)
    readA(cb, 1);
    mmaq(1);
    readA(cb, 2);
    if (t + 2 < T) stageB4(bsel == 0 ? 2 : bsel - 1);   // (t+2)%3
    mmaq(2);
    readA(cb, 3);
    mmaq(3);
    // counted ladder: steady keeps B(t+2) (newest 4) in flight
    if (t + 2 < T) {
      asm volatile("s_waitcnt vmcnt(4)" ::: "memory");
    } else if (t + 1 < T) {
      asm volatile("s_waitcnt vmcnt(0)" ::: "memory");
    }
    BARRIER();
    bsel = bsel == 2 ? 0 : bsel + 1;
  }

  // ---- epilogue ----
  if (EPI == 2) {
    // fp32 += : already full-sector stores
#pragma unroll
    for (int nt = 0; nt < 4; nt++) {
      int c = col0 + widn * 64 + nt * 16 + lr;
      float bv = bias ? bias[c] : 0.f;
#pragma unroll
      for (int mi = 0; mi < 8; mi++) {
        long rb = row0 + widm * 128 + mi * 16 + lq4 * 4;
#pragma unroll
        for (int reg = 0; reg < 4; reg++) {
          float v = acc[mi][nt][reg] + bv;
          long idx = cOff + (rb + reg) * (long)ldc + c;
          Cf[idx] += v;
        }
      }
    }
  } else {
    // bf16 outputs (EPI 1/4): LDS-transposed coalesced stores.
    // Per-wave scratch 64 rows x 72-elem stride (4-row group = 144 dwords
    // === 16 mod 32 -> 2-way both sides = free); 2 passes of 64 rows;
    // dwordx4 global stores = 8 rows x 128B full lines per instruction.
    // sm reusable: final tile barrier passed, no gloads outstanding.
    bf16* scr = sm + wid * (64 * 72);
    const int rr = lane >> 3, ccol = (lane & 7) * 8;
#pragma unroll
    for (int p = 0; p < 2; p++) {
#pragma unroll
      for (int nt = 0; nt < 4; nt++) {
        int c = col0 + widn * 64 + nt * 16 + lr;
        float bv = bias ? bias[c] : 0.f;
#pragma unroll
        for (int ml = 0; ml < 4; ml++) {
#pragma unroll
          for (int reg = 0; reg < 4; reg++) {
            float v = acc[p * 4 + ml][nt][reg] + bv;
            if (EPI == 4) v = 0.5f * v * (1.f + fast_erff(v * 0.70710678118654752f));
            scr[(ml * 16 + lq4 * 4 + reg) * 72 + nt * 16 + lr] = (bf16)v;
          }
        }
      }
#pragma unroll
      for (int it = 0; it < 8; it++) {
        int r = it * 8 + rr;
        uint4 v = *(const uint4*)&scr[r * 72 + ccol];
        long grow = row0 + widm * 128 + p * 64 + r;
        *(uint4*)&Cb[cOff + grow * (long)ldc + col0 + widn * 64 + ccol] = v;
      }
    }
  }
}

// ---------------------------------------------------------------------------
// Generic MFMA GEMM (legacy 128x128): used for xW1 (AMODE1), linear-out,
// final W2 (AMODE2). 256 threads (4 waves, 2x2), z-batched, XCD-swizzled.
// ---------------------------------------------------------------------------
__global__ __launch_bounds__(256) void gemm_bt(
    const void* __restrict__ Avoid, const bf16* __restrict__ Bt,
    const float* __restrict__ bias, float* __restrict__ Cf, bf16* __restrict__ Cb,
    int K, int lda, int ldb, int ldc, int EPI, int AMODE,
    long aBatch, long bBatch, int zdiv, long cOuter, long cInner) {
  __shared__ __align__(16) bf16 As0[128 * 32];
  __shared__ __align__(16) bf16 As1[128 * 32];
  __shared__ __align__(16) bf16 Bs0[128 * 32];
  __shared__ __align__(16) bf16 Bs1[128 * 32];
  const int tid = threadIdx.x;

  const int nx = gridDim.x, ny = gridDim.y;
  const long nwg = (long)nx * ny * gridDim.z;
  const long fid = blockIdx.x + (long)nx * (blockIdx.y + (long)ny * blockIdx.z);
  const long cq = nwg >> 3, cr = nwg & 7;
  const long xcd = fid & 7, ofs = fid >> 3;
  const long swz = (xcd < cr ? xcd * (cq + 1) : cr * (cq + 1) + (xcd - cr) * cq) + ofs;
  const int bx = (int)(swz % nx);
  const int by = (int)((swz / nx) % ny);
  const int bz = (int)(swz / ((long)nx * ny));

  Bt += (long)bz * bBatch;
  const long cOff = (long)(bz / zdiv) * cOuter + (long)(bz % zdiv) * cInner;
  const int row0 = by * 128;
  const int col0 = bx * 128;
  const int lane = tid & 63, wid = tid >> 6;
  const int wm = (wid & 1) * 64, wn = (wid >> 1) * 64;
  const int lr = lane & 15, lk = (lane >> 4) * 8;

  floatx4 acc[4][4];
#pragma unroll
  for (int i = 0; i < 4; i++)
#pragma unroll
    for (int j = 0; j < 4; j++) acc[i][j] = {0.f, 0.f, 0.f, 0.f};

  if (AMODE == 0) {
    const bf16* A = (const bf16*)Avoid + (long)bz * aBatch;
    const bf16* pAa = A + (long)(row0 + wid * 16 + (lane >> 2)) * lda + (lane & 3) * 8;
    const bf16* pBa = Bt + (long)(col0 + wid * 16 + (lane >> 2)) * ldb + (lane & 3) * 8;
    bf16* ldsA0 = &As0[wid * 16 * 32];
    bf16* ldsA1 = &As1[wid * 16 * 32];
    bf16* ldsB0 = &Bs0[wid * 16 * 32];
    bf16* ldsB1 = &Bs1[wid * 16 * 32];
    const long a64 = (long)64 * lda, b64 = (long)64 * ldb;

    auto stage = [&](bf16* dA, bf16* dB) {
      gload_lds16(pAa, dA);
      gload_lds16(pAa + a64, dA + 64 * 32);
      gload_lds16(pBa, dB);
      gload_lds16(pBa + b64, dB + 64 * 32);
      pAa += 32; pBa += 32;
    };
    auto compute = [&](const bf16* AS, const bf16* BS) {
      short8 af[4], bfr[4];
#pragma unroll
      for (int mt = 0; mt < 4; mt++) af[mt] = *(const short8*)(&AS[(wm + mt * 16 + lr) * 32 + lk]);
#pragma unroll
      for (int nt = 0; nt < 4; nt++) bfr[nt] = *(const short8*)(&BS[(wn + nt * 16 + lr) * 32 + lk]);
#pragma unroll
      for (int mt = 0; mt < 4; mt++)
#pragma unroll
        for (int nt = 0; nt < 4; nt++)
          acc[mt][nt] = MFMA16(af[mt], bfr[nt], acc[mt][nt]);
    };

    stage(ldsA0, ldsB0);
    __syncthreads();
    for (int k0 = 0; k0 < K; k0 += 64) {
      stage(ldsA1, ldsB1);
      compute(As0, Bs0);
      __syncthreads();
      if (k0 + 64 < K) stage(ldsA0, ldsB0);
      compute(As1, Bs1);
      __syncthreads();
    }
  } else {
    const float* Af = (const float*)Avoid;
    const int srow = tid >> 2;
    const int skcol = (tid & 3) * 8;
    const long r0 = row0 + srow, r1 = r0 + 64;
    const bf16* pB = Bt + (long)(col0 + srow) * ldb + skcol;
    const int ldsOff = srow * 32 + skcol;
    const float* pF0; const float* pF1;
    bool v0 = true, v1 = true;
    if (AMODE == 1) {
      int t0 = (int)(r0 & (SEQ - 1)), t1 = (int)(r1 & (SEQ - 1));
      v0 = t0 < NREAL; v1 = t1 < NREAL;
      if (!v0) t0 = 0;
      if (!v1) t1 = 0;
      pF0 = Af + ((r0 >> 12) * NREAL + t0) * DINP + skcol;
      pF1 = Af + ((r1 >> 12) * NREAL + t1) * DINP + skcol;
    } else {
      pF0 = Af + r0 * lda + skcol;
      pF1 = Af + r1 * lda + skcol;
    }
    for (int k0 = 0; k0 < K; k0 += 32) {
      uint4 b0 = *(const uint4*)(pB);
      uint4 b1 = *(const uint4*)(pB + (long)64 * ldb);
      pB += 32;
      uint4 a0 = {0, 0, 0, 0}, a1 = {0, 0, 0, 0};
      if (v0) a0 = pack8(pF0);
      if (v1) a1 = pack8(pF1);
      pF0 += 32; pF1 += 32;
      __syncthreads();
      *(uint4*)(&As0[ldsOff]) = a0;
      *(uint4*)(&As0[ldsOff + 64 * 32]) = a1;
      *(uint4*)(&Bs0[ldsOff]) = b0;
      *(uint4*)(&Bs0[ldsOff + 64 * 32]) = b1;
      __syncthreads();
      short8 af[4], bfr[4];
#pragma unroll
      for (int mt = 0; mt < 4; mt++) af[mt] = *(const short8*)(&As0[(wm + mt * 16 + lr) * 32 + lk]);
#pragma unroll
      for (int nt = 0; nt < 4; nt++) bfr[nt] = *(const short8*)(&Bs0[(wn + nt * 16 + lr) * 32 + lk]);
#pragma unroll
      for (int mt = 0; mt < 4; mt++)
#pragma unroll
        for (int nt = 0; nt < 4; nt++)
          acc[mt][nt] = MFMA16(af[mt], bfr[nt], acc[mt][nt]);
    }
  }

#pragma unroll
  for (int nt = 0; nt < 4; nt++) {
    int c = col0 + wn + nt * 16 + lr;
    float bv = 0.f;
    if (bias) {
      if (EPI == 5) { if (c < 64) bv = bias[c]; }
      else bv = bias[c];
    }
#pragma unroll
    for (int mt = 0; mt < 4; mt++) {
      long rb = row0 + wm + mt * 16 + (lane >> 4) * 4;
#pragma unroll
      for (int reg = 0; reg < 4; reg++) {
        float v = acc[mt][nt][reg] + bv;
        long ri = rb + reg;
        long idx = cOff + ri * (long)ldc + c;
        if (EPI == 0) Cf[idx] = fast_tanhf(v);
        else if (EPI == 1) Cb[idx] = (bf16)v;
        else if (EPI == 2) Cf[idx] += v;
        else if (EPI == 4) { float g = 0.5f * v * (1.f + fast_erff(v * 0.70710678118654752f)); Cb[idx] = (bf16)g; }
        else if (EPI == 5) {
          int bb = (int)(ri >> 12); int tt = (int)(ri & (SEQ - 1));
          if (tt < NREAL && c < 64) Cf[((long)bb * NREAL + tt) * 64 + c] = v;
        }
      }
    }
  }
}

// ---------------------------------------------------------------------------
// LayerNorm over 512 fp32 -> bf16. One wave per row, 4 rows per block.
// ---------------------------------------------------------------------------
__global__ __launch_bounds__(256) void ln_kernel(const float* __restrict__ h,
                                                 const float* __restrict__ g,
                                                 const float* __restrict__ bta,
                                                 bf16* __restrict__ out) {
  int wid = threadIdx.x >> 6, lane = threadIdx.x & 63;
  long row = (long)blockIdx.x * 4 + wid;
  const float* src = h + row * DM + lane * 8;
  float4 a = *(const float4*)(src);
  float4 b = *(const float4*)(src + 4);
  float x[8] = {a.x, a.y, a.z, a.w, b.x, b.y, b.z, b.w};
  float s = 0.f, sq = 0.f;
#pragma unroll
  for (int i = 0; i < 8; i++) { s += x[i]; sq += x[i] * x[i]; }
#pragma unroll
  for (int m = 32; m >= 1; m >>= 1) { s += __shfl_xor(s, m, 64); sq += __shfl_xor(sq, m, 64); }
  float mu = s * (1.f / DM);
  float var = sq * (1.f / DM) - mu * mu;
  float rstd = rsqrtf(var + 1e-5f);
  const float* gp = g + lane * 8;
  const float* bp = bta + lane * 8;
  bf16* dst = out + row * DM + lane * 8;
#pragma unroll
  for (int i = 0; i < 8; i++)
    dst[i] = (bf16)((x[i] - mu) * rstd * gp[i] + bp[i]);
}

// ---------------------------------------------------------------------------
// Local attention, head 0. Grid (2 halves, 32 windows, GB batches).
// ---------------------------------------------------------------------------
__global__ __launch_bounds__(256) void local_attn(const bf16* __restrict__ q,
                                                  const bf16* __restrict__ k,
                                                  const bf16* __restrict__ v,
                                                  bf16* __restrict__ att) {
  int half = blockIdx.x, w = blockIdx.y, b = blockIdx.z;
  int tid = threadIdx.x, wid = tid >> 6, lane = tid & 63;
  int lr = lane & 15, lq4 = lane >> 4;
  __shared__ __align__(16) bf16 Ks[32 * 128];   // [j][d]
  __shared__ __align__(16) bf16 Vts[128 * 32];  // [d][j]
  __shared__ __align__(16) bf16 Ps[4][16 * 32]; // per-wave P scratch

  int t0 = w * 128 + half * 64 + wid * 16;
  long qbase = ((long)b * SEQ + t0 + lr) * DM;
  short8 qf[4];
#pragma unroll
  for (int ks = 0; ks < 4; ks++) qf[ks] = *(const short8*)(q + qbase + ks * 32 + lq4 * 8);

  floatx4 Oacc[8];
#pragma unroll
  for (int i = 0; i < 8; i++) Oacc[i] = {0.f, 0.f, 0.f, 0.f};
  float rs[4] = {0.f, 0.f, 0.f, 0.f};

  int keystart = w * 128 - 128;
  for (int ch = 0; ch < 12; ch++) {
    int kb = keystart + ch * 32;
    if (kb < 0 || kb >= SEQ) continue;  // uniform per block
    {
      int j = tid >> 3, d = (tid & 7) * 16;
      const bf16* ksrc = k + ((long)b * SEQ + kb + j) * DM + d;
      *(uint4*)(&Ks[j * 128 + d]) = *(const uint4*)(ksrc);
      *(uint4*)(&Ks[j * 128 + d + 8]) = *(const uint4*)(ksrc + 8);
      const bf16* vsrc = v + ((long)b * SEQ + kb + j) * DM + d;
#pragma unroll
      for (int e = 0; e < 16; e++) Vts[(d + e) * 32 + j] = vsrc[e];
    }
    __syncthreads();
    floatx4 s0 = {0.f, 0.f, 0.f, 0.f}, s1 = {0.f, 0.f, 0.f, 0.f};
#pragma unroll
    for (int ks = 0; ks < 4; ks++) {
      short8 kf0 = *(const short8*)(&Ks[(0 + lr) * 128 + ks * 32 + lq4 * 8]);
      short8 kf1 = *(const short8*)(&Ks[(16 + lr) * 128 + ks * 32 + lq4 * 8]);
      s0 = MFMA16(qf[ks], kf0, s0);
      s1 = MFMA16(qf[ks], kf1, s1);
    }
#pragma unroll
    for (int reg = 0; reg < 4; reg++) {
      float e0 = __expf(s0[reg] * 0.08838834764831845f);
      float e1 = __expf(s1[reg] * 0.08838834764831845f);
      rs[reg] += e0 + e1;
      Ps[wid][(lq4 * 4 + reg) * 32 + lr] = (bf16)e0;
      Ps[wid][(lq4 * 4 + reg) * 32 + 16 + lr] = (bf16)e1;
    }
    __syncthreads();
    short8 pf = *(const short8*)(&Ps[wid][lr * 32 + lq4 * 8]);
#pragma unroll
    for (int nt = 0; nt < 8; nt++) {
      short8 vf = *(const short8*)(&Vts[(nt * 16 + lr) * 32 + lq4 * 8]);
      Oacc[nt] = MFMA16(pf, vf, Oacc[nt]);
    }
    __syncthreads();
  }
#pragma unroll
  for (int m = 1; m < 16; m <<= 1)
#pragma unroll
    for (int reg = 0; reg < 4; reg++) rs[reg] += __shfl_xor(rs[reg], m, 64);
  long obase = ((long)b * SEQ + t0 + lq4 * 4) * DM;
#pragma unroll
  for (int nt = 0; nt < 8; nt++)
#pragma unroll
    for (int reg = 0; reg < 4; reg++)
      att[obase + (long)reg * DM + nt * 16 + lr] = (bf16)(Oacc[nt][reg] / rs[reg]);
}

// ---------------------------------------------------------------------------
// Linear-attn q-softmax: qp[z][t][128] = softmax(q_head)*d^-0.5, z=lb*3+h2
// ---------------------------------------------------------------------------
__global__ __launch_bounds__(256) void qp_softmax(const bf16* __restrict__ q, bf16* __restrict__ qp) {
  int wid = threadIdx.x >> 6, lane = threadIdx.x & 63;
  long task = (long)blockIdx.x * 4 + wid;
  int tt = (int)(task & (SEQ - 1));
  int z6 = (int)(task >> 12);
  int lb = z6 / 3, h2 = z6 % 3;
  const bf16* src = q + ((long)lb * SEQ + tt) * DM + (h2 + 1) * 128 + lane * 2;
  float x0 = (float)src[0], x1 = (float)src[1];
  float m = fmaxf(x0, x1);
#pragma unroll
  for (int s = 32; s >= 1; s >>= 1) m = fmaxf(m, __shfl_xor(m, s, 64));
  float e0 = __expf(x0 - m), e1 = __expf(x1 - m);
  float sm = e0 + e1;
#pragma unroll
  for (int s = 32; s >= 1; s >>= 1) sm += __shfl_xor(sm, s, 64);
  float inv = 0.08838834764831845f / sm;
  bf16* dst = qp + task * 128 + lane * 2;
  dst[0] = (bf16)(e0 * inv);
  dst[1] = (bf16)(e1 * inv);
}

// ---------------------------------------------------------------------------
// k column stats, phase 1: per-(z, 128-row chunk) column max and exp-sum.
// ---------------------------------------------------------------------------
__global__ __launch_bounds__(128) void kstats_part(const bf16* __restrict__ k,
                                                   float* __restrict__ part, int lOff) {
  int chunk = blockIdx.x, z = blockIdx.y;
  int lb = z / 3, h2 = z % 3, ch = (h2 + 1) * 128;
  int d = threadIdx.x;
  const bf16* base = k + ((long)lb * SEQ + chunk * 128) * DM + ch + d;
  float m = -1e30f;
#pragma unroll 4
  for (int t = 0; t < 128; t++) m = fmaxf(m, (float)base[(long)t * DM]);
  float l = 0.f;
#pragma unroll 4
  for (int t = 0; t < 128; t++) l += __expf((float)base[(long)t * DM] - m);
  int idx = (z * 32 + chunk) * 128 + d;
  part[idx] = m;
  part[lOff + idx] = l;
}

// phase 2: combine 32 chunk stats -> kml[z*256+d]=M, +128=L
__global__ __launch_bounds__(128) void kstats_comb(const float* __restrict__ part,
                                                   float* __restrict__ kml, int lOff) {
  int z = blockIdx.x, d = threadIdx.x;
  float M = -1e30f;
#pragma unroll 4
  for (int c = 0; c < 32; c++) M = fmaxf(M, part[(z * 32 + c) * 128 + d]);
  float L = 0.f;
#pragma unroll 4
  for (int c = 0; c < 32; c++) {
    int i = (z * 32 + c) * 128 + d;
    L += part[lOff + i] * __expf(part[i] - M);
  }
  kml[z * 256 + d] = M;
  kml[z * 256 + 128 + d] = L;
}

// ---------------------------------------------------------------------------
// ctx via MFMA: part[z][chunk][e*128+d] = sum_{t in 512-chunk} v[t][e]*k'[t][d]
// ---------------------------------------------------------------------------
__global__ __launch_bounds__(256) void ctx_mfma(const bf16* __restrict__ k,
                                                const bf16* __restrict__ v,
                                                const float* __restrict__ kml,
                                                float* __restrict__ part) {
  int chunk = blockIdx.x, z = blockIdx.y;
  int lb = z / 3, h2 = z % 3, ch = (h2 + 1) * 128;
  int tid = threadIdx.x, lane = tid & 63, wid = tid >> 6;
  const int wm = (wid & 1) * 64, wn = (wid >> 1) * 64;
  const int lr = lane & 15, lk = (lane >> 4) * 8;
  __shared__ float ml2[128];
  __shared__ __align__(16) bf16 Vt[128 * CS];
  __shared__ __align__(16) bf16 Kt[128 * CS];
  if (tid < 128)
    ml2[tid] = kml[z * 256 + tid] + logf(kml[z * 256 + 128 + tid]);

  int j = tid >> 3, d0 = (tid & 7) * 16;
  const bf16* vsrc = v + ((long)lb * SEQ + chunk * 512 + j) * DM + ch + d0;
  const bf16* ksrc = k + ((long)lb * SEQ + chunk * 512 + j) * DM + ch + d0;

  floatx4 acc[4][4];
#pragma unroll
  for (int i = 0; i < 4; i++)
#pragma unroll
    for (int jj = 0; jj < 4; jj++) acc[i][jj] = {0.f, 0.f, 0.f, 0.f};

  for (int s = 0; s < 16; s++) {
    union { bf16 h[16]; uint4 u[2]; } va, ka;
    va.u[0] = *(const uint4*)(vsrc); va.u[1] = *(const uint4*)(vsrc + 8);
    ka.u[0] = *(const uint4*)(ksrc); ka.u[1] = *(const uint4*)(ksrc + 8);
    vsrc += (long)32 * DM; ksrc += (long)32 * DM;
    __syncthreads();
#pragma unroll
    for (int e = 0; e < 16; e++) {
      Vt[(d0 + e) * CS + j] = va.h[e];
      Kt[(d0 + e) * CS + j] = (bf16)__expf((float)ka.h[e] - ml2[d0 + e]);
    }
    __syncthreads();
    short8 af[4], bfr[4];
#pragma unroll
    for (int mt = 0; mt < 4; mt++) af[mt] = *(const short8*)(&Vt[(wm + mt * 16 + lr) * CS + lk]);
#pragma unroll
    for (int nt = 0; nt < 4; nt++) bfr[nt] = *(const short8*)(&Kt[(wn + nt * 16 + lr) * CS + lk]);
#pragma unroll
    for (int mt = 0; mt < 4; mt++)
#pragma unroll
      for (int nt = 0; nt < 4; nt++)
        acc[mt][nt] = MFMA16(af[mt], bfr[nt], acc[mt][nt]);
  }

  float* dst = part + ((long)z * 8 + chunk) * 16384;
#pragma unroll
  for (int nt = 0; nt < 4; nt++) {
    int c = wn + nt * 16 + lr;
#pragma unroll
    for (int mt = 0; mt < 4; mt++) {
      int rb = wm + mt * 16 + (lane >> 4) * 4;
#pragma unroll
      for (int reg = 0; reg < 4; reg++)
        dst[(rb + reg) * 128 + c] = acc[mt][nt][reg];
    }
  }
}

__global__ __launch_bounds__(256) void ctx_reduce(const float* __restrict__ part, bf16* __restrict__ ctxT) {
  long i = (long)blockIdx.x * 256 + threadIdx.x;
  int z = (int)(i >> 14);
  int off = (int)(i & 16383);
  float s = 0.f;
#pragma unroll
  for (int c = 0; c < 8; c++) s += part[(((long)z * 8 + c) << 14) + off];
  ctxT[i] = (bf16)s;
}

// ---------------------------------------------------------------------------
extern "C" void kernel_launch(void* const* d_in, const int* in_sizes, int n_in,
                              void* d_out, int out_size, void* d_ws, size_t ws_size,
                              hipStream_t stream) {
  float* outp = (float*)d_out;

  // ---- adaptive arena: pick largest GB in {8,4,2} that fits ws_size ----
  long offH = 0;
  int GB = 0;
  long offLNG, offQ, offK, offV, offATT, offCTXP, offCTXT, offKML, offWT, need;
  for (int gb = 8; gb >= 2; gb >>= 1) {
    long sLN = (long)gb * 4194304;
    offLNG = 67108864L;
    offQ   = offLNG + sLN;
    offK   = offQ + sLN;
    offV   = offK + sLN;
    offATT = offV + sLN;
    offCTXP= offATT + sLN;
    offCTXT= offCTXP + (long)gb * 1572864;
    offKML = offCTXT + (long)gb * 98304;
    offWT  = offKML + (long)gb * 3072;
    need   = offWT + 6553600L;
    if ((size_t)need <= ws_size) { GB = gb; break; }
  }
  if (GB == 0) {
    beacon<<<(out_size + 255) / 256, 256, 0, stream>>>(outp, out_size);
    return;
  }
  const int NG = NBAT / GB;            // groups
  const long GR = (long)GB * SEQ;      // rows per group
  const int NZ = GB * 3;               // linear-attn (batch,head) pairs per group

  const float* x   = (const float*)d_in[0];
  const float* W1  = (const float*)d_in[1];
  const float* b1  = (const float*)d_in[2];
  const float* g1  = (const float*)d_in[3];
  const float* be1 = (const float*)d_in[4];
  const float* Wq  = (const float*)d_in[5];
  const float* Wk  = (const float*)d_in[6];
  const float* Wv  = (const float*)d_in[7];
  const float* Wo  = (const float*)d_in[8];
  const float* bo  = (const float*)d_in[9];
  const float* g2  = (const float*)d_in[10];
  const float* be2 = (const float*)d_in[11];
  const float* Wf1 = (const float*)d_in[12];
  const float* bf1 = (const float*)d_in[13];
  const float* Wf2 = (const float*)d_in[14];
  const float* bf2 = (const float*)d_in[15];
  const float* W2  = (const float*)d_in[16];
  const float* b2  = (const float*)d_in[17];

  char* ws = (char*)d_ws;
  float* h   = (float*)(ws + offH);
  bf16* lnG  = (bf16*)(ws + offLNG);
  bf16* qp   = (bf16*)(ws + offLNG);   // overlays lnG (lnG dead after QKV; qp dead in FFN)
  bf16* qb   = (bf16*)(ws + offQ);
  bf16* kb   = (bf16*)(ws + offK);
  bf16* vb   = (bf16*)(ws + offV);
  bf16* attb = (bf16*)(ws + offATT);
  bf16* ff1g = (bf16*)(ws + offQ);     // overlays q..attn (dead in FFN phase)
  float* ctxp= (float*)(ws + offCTXP);
  bf16* ctxT = (bf16*)(ws + offCTXT);
  float* kml = (float*)(ws + offKML);
  bf16* wt   = (bf16*)(ws + offWT);
  bf16* wqt  = wt + 65536;
  bf16* wot  = wt + 851968;
  bf16* wf1t = wt + 1114112;
  bf16* wf2t = wt + 2162688;
  bf16* w2t  = wt + 3211264;
  const int lOff = NZ * 32 * 128;      // kstats l-plane offset within ctxp

  // ---- all weight transposes (fp32 -> bf16, [Npad][K] K-contiguous) ----
  transpose8<<<dim3(32, 32, 8), 256, 0, stream>>>(W1, Wq, Wk, Wv, Wo, Wf1, Wf2, W2, wt);

  // ---- h = tanh(xpad @ W1 + b1) fp32; pad rows handled in A staging ----
  gemm_bt<<<dim3(4, 256, 1), 256, 0, stream>>>(x, wt, b1, h, nullptr,
      DINP, DINP, DINP, DM, 0, 1, 0, 0, 1, 0, 0);

  // ---- attention, NG groups of GB batches ----
  for (int g = 0; g < NG; g++) {
    float* hg = h + (long)g * GR * DM;
    ln_kernel<<<(int)(GR / 4), 256, 0, stream>>>(hg, g1, be1, lnG);
    // Q,K,V in one z=3 batched launch (outputs land in qb,kb,vb = contiguous)
    gemm256<<<dim3(2, (int)(GR / 256), 3), 512, 0, stream>>>(lnG, wqt, nullptr, nullptr, qb,
        DM, DM, DM, DM, 1,
        0L, 262144L, 3, 0L, GR * DM);

    local_attn<<<dim3(2, 32, GB), 256, 0, stream>>>(qb, kb, vb, attb);

    qp_softmax<<<NZ * 1024, 256, 0, stream>>>(qb, qp);
    kstats_part<<<dim3(32, NZ), 128, 0, stream>>>(kb, ctxp, lOff);
    kstats_comb<<<NZ, 128, 0, stream>>>(ctxp, kml, lOff);
    ctx_mfma<<<dim3(8, NZ), 256, 0, stream>>>(kb, vb, kml, ctxp);
    ctx_reduce<<<NZ * 64, 256, 0, stream>>>(ctxp, ctxT);
    gemm_bt<<<dim3(1, 32, NZ), 256, 0, stream>>>(qp, ctxT, nullptr, nullptr, attb + 128,
        128, 128, 128, DM, 1, 0,
        (long)SEQ * 128, 16384L, 3, (long)SEQ * DM, 128L);

    // h += attn @ Wo + bo : 256-tile, block-owned +=
    gemm256<<<dim3(2, (int)(GR / 256), 1), 512, 0, stream>>>(attb, wot, bo, hg, nullptr,
        DM, DM, DM, DM, 2, 0, 0, 1, 0, 0);
  }

  // ---- FFN, NG groups ----
  for (int g = 0; g < NG; g++) {
    float* hg = h + (long)g * GR * DM;
    ln_kernel<<<(int)(GR / 4), 256, 0, stream>>>(hg, g2, be2, lnG);
    gemm256<<<dim3(8, (int)(GR / 256), 1), 512, 0, stream>>>(lnG, wf1t, bf1, nullptr, ff1g,
        DM, DM, DM, DFF, 4, 0, 0, 1, 0, 0);
    // h += gelu(ff1) @ Wf2 + bf2 : 256-tile, block-owned +=
    gemm256<<<dim3(2, (int)(GR / 256), 1), 512, 0, stream>>>(ff1g, wf2t, bf2, hg, nullptr,
        DFF, DFF, DFF, DM, 2, 0, 0, 1, 0, 0);
  }

  // ---- out = (h @ W2 + b2)[:, :3000, :] -> d_out fp32 (h staged as bf16) ----
  gemm_bt<<<dim3(1, 256, 1), 256, 0, stream>>>(h, w2t, b2, outp, nullptr,
      DM, DM, DM, 64, 5, 2, 0, 0, 1, 0, 0);
}

// Round 10
// 601.642 us; speedup vs baseline: 1.1310x; 1.0807x over previous
//
#include <hip/hip_runtime.h>
#include <hip/hip_bf16.h>
#include <hip/hip_fp16.h>
#include <math.h>

// ---------------------------------------------------------------------------
// Linear_Transformer on MI355X (gfx950). fp32 I/O, bf16 MFMA internals,
// fp16 residual stream.
// Round 20: OPERATOR-LEVEL pivot after six null schedule variants (FF1
// pinned 117-127us; K=512 = 8 tiles/block is end-dominated, outside the
// guide's measured K=4096 regime). (1) residual h fp32 -> fp16: halves the
// ~448MB of h traffic (xW1 write, 2x LN read, attn-out RMW, FF2 RMW, W2
// read). Accuracy: fp16 quantum (2^-10 @ |h|~1) is 4x below the bf16
// quantization already on every GEMM input (current absmax 0.0039 = bf16
// floor). (2) gemm256 EPI=2 -> LDS-transposed COALESCED fp16 RMW (uint4
// load+add+store, full 128B lines; avoids R4's partial-sector write
// amplification). (3) swizzle decomposition z-fastest: QKV's 3 z-slices of
// one (bx,by) sit adjacent in an XCD chunk -> shared lnG A-stripe read once
// per XCD instead of 3x. K-loop (R9 counted-vmcnt 3-buffer B) unchanged.
// ---------------------------------------------------------------------------

typedef __hip_bfloat16 bf16;
typedef __attribute__((ext_vector_type(8))) short short8;   // 8 bf16 (MFMA A/B frag)
typedef __attribute__((ext_vector_type(4))) float floatx4;  // MFMA C/D frag

#define SEQ   4096
#define NBAT  8
#define DM    512
#define DINP  128
#define DFF   2048
#define NREAL 3000
#define CS    40              // ctx_mfma LDS stride (80B, 16B-aligned)

#define MFMA16(a,b,c) __builtin_amdgcn_mfma_f32_16x16x32_bf16((a),(b),(c),0,0,0)
#define BARRIER() asm volatile("s_barrier" ::: "memory")

// async global->LDS, 16B per lane, deposits at lds + lane*16
__device__ __forceinline__ void gload_lds16(const void* g, void* l) {
  auto* gp = reinterpret_cast<const __attribute__((address_space(1))) unsigned int*>(
      reinterpret_cast<uintptr_t>(g));
  auto* lp = reinterpret_cast<__attribute__((address_space(3))) unsigned int*>(
      reinterpret_cast<uintptr_t>(l));
  __builtin_amdgcn_global_load_lds(gp, lp, 16, 0, 0);
}

// opaque LDS 16B read: compiler sees no memory access -> no auto s_waitcnt.
// Caller MUST wait lgkmcnt + sched_barrier(0) before consuming (rule #18).
__device__ __forceinline__ short8 lds_read128(const bf16* p) {
  auto* lp = reinterpret_cast<const __attribute__((address_space(3))) bf16*>(
      reinterpret_cast<uintptr_t>(p));
  short8 r;
  asm volatile("ds_read_b128 %0, %1" : "=v"(r) : "v"(lp));
  return r;
}

// branch-free erf, Abramowitz-Stegun 7.1.26, |eps| <= 1.5e-7
__device__ __forceinline__ float fast_erff(float x) {
  float ax = fabsf(x);
  float t = __builtin_amdgcn_rcpf(fmaf(0.3275911f, ax, 1.f));
  float p = fmaf(fmaf(fmaf(fmaf(1.061405429f, t, -1.453152027f), t,
                           1.421413741f), t, -0.284496736f), t, 0.254829592f) * t;
  float r = 1.f - p * __expf(-ax * ax);
  return copysignf(r, x);
}

// tanh(x) = 1 - 2/(e^{2x}+1); saturates correctly at +-inf
__device__ __forceinline__ float fast_tanhf(float x) {
  float e = __expf(2.f * x);
  return 1.f - 2.f * __builtin_amdgcn_rcpf(e + 1.f);
}

// ---------------------------------------------------------------------------
__global__ __launch_bounds__(256) void beacon(float* __restrict__ out, long n) {
  long i = (long)blockIdx.x * 256 + threadIdx.x;
  if (i < n) out[i] = 10000.f;
}

// ---------------------------------------------------------------------------
// All 8 weight transposes in one launch. Wt[n][k] = n<N ? (bf16)W[k][n] : 0
// ---------------------------------------------------------------------------
__global__ __launch_bounds__(256) void transpose8(
    const float* __restrict__ W1, const float* __restrict__ Wq,
    const float* __restrict__ Wk, const float* __restrict__ Wv,
    const float* __restrict__ Wo, const float* __restrict__ Wf1,
    const float* __restrict__ Wf2, const float* __restrict__ W2,
    bf16* __restrict__ wt) {
  const int Ks[8]   = {128, 512, 512, 512, 512, 512, 2048, 512};
  const int Ns[8]   = {512, 512, 512, 512, 512, 2048, 512, 64};
  const int Nps[8]  = {512, 512, 512, 512, 512, 2048, 512, 128};
  const long Ofs[8] = {0L, 65536L, 327680L, 589824L, 851968L, 1114112L, 2162688L, 3211264L};
  int zi = blockIdx.z;
  int K = Ks[zi], N = Ns[zi], Npad = Nps[zi];
  int k0 = blockIdx.x * 64, n0 = blockIdx.y * 64;
  if (k0 >= K || n0 >= Npad) return;
  const float* W = zi == 0 ? W1 : zi == 1 ? Wq : zi == 2 ? Wk : zi == 3 ? Wv
                 : zi == 4 ? Wo : zi == 5 ? Wf1 : zi == 6 ? Wf2 : W2;
  bf16* Wt = wt + Ofs[zi];
  __shared__ float t[64][65];
  int r = threadIdx.x >> 2, c = (threadIdx.x & 3) * 16;
#pragma unroll
  for (int i = 0; i < 16; i++) {
    int n = n0 + c + i;
    t[r][c + i] = (n < N) ? W[(long)(k0 + r) * N + n] : 0.f;
  }
  __syncthreads();
#pragma unroll
  for (int i = 0; i < 16; i++)
    Wt[(long)(n0 + r) * K + k0 + c + i] = (bf16)t[c + i][r];
}

// ---------------------------------------------------------------------------
__device__ inline uint4 pack8(const float* p) {
  union { bf16 h[8]; uint4 u; } r;
  float4 a = *(const float4*)p;
  float4 b = *(const float4*)(p + 4);
  r.h[0] = (bf16)a.x; r.h[1] = (bf16)a.y; r.h[2] = (bf16)a.z; r.h[3] = (bf16)a.w;
  r.h[4] = (bf16)b.x; r.h[5] = (bf16)b.y; r.h[6] = (bf16)b.z; r.h[7] = (bf16)b.w;
  return r.u;
}

__device__ inline uint4 pack8h(const __half* p) {
  union { __half h[8]; uint4 u; } s;
  s.u = *(const uint4*)p;
  union { bf16 h[8]; uint4 u; } r;
#pragma unroll
  for (int i = 0; i < 8; i++) r.h[i] = (bf16)(float)s.h[i];
  return r.u;
}

// ---------------------------------------------------------------------------
// gemm256: 256x256 MFMA GEMM. C[M x N] = epi(A @ Bt^T + bias).
// 512 threads = 8 waves (2M x 4N), per-wave C = 128x64. BK=64 per K-tile.
// A: 2-buffer (64KB); B: 3-buffer rotation (96KB); 160KB LDS total.
// Counted vmcnt(4) per tile keeps B(t+2)'s loads in flight across the
// single tile-end barrier. z-fastest block decomposition (QKV A-reuse).
// EPI: 1 bf16->Cb  2 fp16 h += (coalesced RMW)  4 gelu->Cb
// ---------------------------------------------------------------------------
__global__ __launch_bounds__(512, 2) void gemm256(
    const bf16* __restrict__ A, const bf16* __restrict__ Bt,
    const float* __restrict__ bias, __half* __restrict__ Ch, bf16* __restrict__ Cb,
    int K, int lda, int ldb, int ldc, int EPI,
    long aBatch, long bBatch, int zdiv, long cOuter, long cInner) {
  // [A0|A1|B0|B1|B2], each 256 rows x 64 cols bf16 (32 KiB) = 160 KiB
  __shared__ __align__(16) bf16 sm[5 * 256 * 64];
  bf16* const smB = sm + 2 * 16384;
  const int tid = threadIdx.x;
  const int lane = tid & 63, wid = tid >> 6;

  // ---- T1: bijective XCD-chunk swizzle; z-FASTEST decomposition ----
  const int nx = gridDim.x, ny = gridDim.y, nz = gridDim.z;
  const long nwg = (long)nx * ny * nz;
  const long fid = blockIdx.x + (long)nx * (blockIdx.y + (long)ny * blockIdx.z);
  const long cq = nwg >> 3, cr = nwg & 7;
  const long xcd = fid & 7, ofs = fid >> 3;
  const long swz = (xcd < cr ? xcd * (cq + 1) : cr * (cq + 1) + (xcd - cr) * cq) + ofs;
  const int bz = (int)(swz % nz);
  const long s2 = swz / nz;
  const int bx = (int)(s2 % nx);
  const int by = (int)(s2 / nx);

  const bf16* Ab = A + (long)bz * aBatch;
  const bf16* Bb = Bt + (long)bz * bBatch;
  const long cOff = (long)(bz / zdiv) * cOuter + (long)(bz % zdiv) * cInner;
  const int row0 = by * 256;
  const int col0 = bx * 256;

  const int widm = wid >> 2, widn = wid & 3;      // 2 x 4 wave grid
  const int lr = lane & 15, lq4 = lane >> 4;
  const int sw = (lr & 7) << 4;                    // T2 read-side swizzle
  const int k0e = ((0 * 64 + lq4 * 16) ^ sw) >> 1; // kk=0 elem offset in row
  const int k1e = ((1 * 64 + lq4 * 16) ^ sw) >> 1; // kk=1

  // staging: per-wave 8-row slices, pre-swizzled global source (rule #21)
  const int lrow = lane >> 3;                      // row within slice
  const int lch = (lane & 7) ^ lrow;               // swizzled 16B chunk
  const bf16* pAbase = Ab + (long)(row0 + wid * 8 + lrow) * lda + lch * 8;
  const bf16* pBbase = Bb + (long)(col0 + wid * 8 + lrow) * ldb + lch * 8;
  const long a64 = (long)64 * lda, b64 = (long)64 * ldb;
  int kA = 0, kB = 0;

  floatx4 acc[8][4];
#pragma unroll
  for (int i = 0; i < 8; i++)
#pragma unroll
    for (int j = 0; j < 4; j++) acc[i][j] = {0.f, 0.f, 0.f, 0.f};

  // stage full A tile (4 gloads/wave, issued as one FIFO group)
  auto stageA4 = [&](int buf) {
    bf16* base = sm + buf * 16384;
#pragma unroll
    for (int h = 0; h < 2; h++) {
      bf16* d = base + (h * 128 + wid * 8) * 64;
      const bf16* g = pAbase + (long)(h * 2) * a64 + kA;
      gload_lds16(g, d);
      gload_lds16(g + a64, d + 64 * 64);
    }
    kA += 64;
  };
  // stage full B tile into rotation slot (4 gloads/wave)
  auto stageB4 = [&](int slot) {
    bf16* base = smB + slot * 16384;
#pragma unroll
    for (int h = 0; h < 2; h++) {
      bf16* d = base + (h * 128 + wid * 8) * 64;
      const bf16* g = pBbase + (long)(h * 2) * b64 + kB;
      gload_lds16(g, d);
      gload_lds16(g + b64, d + 64 * 64);
    }
    kB += 64;
  };

  short8 bfr[4][2], af[2][2];
  auto readB = [&](int slot) {
    const bf16* base = smB + slot * 16384;
#pragma unroll
    for (int nt = 0; nt < 4; nt++) {
      int colB = widn * 64 + nt * 16 + lr;
      bfr[nt][0] = lds_read128(base + colB * 64 + k0e);
      bfr[nt][1] = lds_read128(base + colB * 64 + k1e);
    }
  };
  auto readA = [&](int buf, int q) {
    const bf16* base = sm + buf * 16384;
#pragma unroll
    for (int m = 0; m < 2; m++) {
      int rowA = widm * 128 + q * 32 + m * 16 + lr;
      af[m][0] = lds_read128(base + rowA * 64 + k0e);
      af[m][1] = lds_read128(base + rowA * 64 + k1e);
    }
  };
  auto mmaq = [&](int q) {
    asm volatile("s_waitcnt lgkmcnt(0)" ::: "memory");
    __builtin_amdgcn_sched_barrier(0);          // rule #18: pin MFMA after wait
    __builtin_amdgcn_s_setprio(1);
#pragma unroll
    for (int m = 0; m < 2; m++)
#pragma unroll
      for (int nt = 0; nt < 4; nt++) {
        acc[q * 2 + m][nt] = MFMA16(af[m][0], bfr[nt][0], acc[q * 2 + m][nt]);
        acc[q * 2 + m][nt] = MFMA16(af[m][1], bfr[nt][1], acc[q * 2 + m][nt]);
      }
    __builtin_amdgcn_s_setprio(0);
  };

  const int T = K >> 6;
  // ---- prologue: A(0), B(0), B(1); newest 4 (=B(1)) stay in flight ----
  stageA4(0);
  stageB4(0);
  stageB4(1);
  asm volatile("s_waitcnt vmcnt(4)" ::: "memory");
  BARRIER();

  int bsel = 0;                        // = t % 3
  for (int t = 0; t < T; t++) {
    const int cb = t & 1, nb = cb ^ 1;
    // p0: tile reads (B all + A q0); stage A(t+1) -> nb
    readB(bsel);
    readA(cb, 0);
    if (t + 1 < T) stageA4(nb);
    mmaq(0);
    // p1..p3: free-running (per-wave lgkm waits only)
    readA(cb, 1);
    mmaq(1);
    readA(cb, 2);
    if (t + 2 < T) stageB4(bsel == 0 ? 2 : bsel - 1);   // (t+2)%3
    mmaq(2);
    readA(cb, 3);
    mmaq(3);
    // counted ladder: steady keeps B(t+2) (newest 4) in flight
    if (t + 2 < T) {
      asm volatile("s_waitcnt vmcnt(4)" ::: "memory");
    } else if (t + 1 < T) {
      asm volatile("s_waitcnt vmcnt(0)" ::: "memory");
    }
    BARRIER();
    bsel = bsel == 2 ? 0 : bsel + 1;
  }

  // ---- epilogue (LDS free: final barrier passed, no gloads outstanding) --
  if (EPI == 2) {
    // fp16 h += : LDS-transpose then coalesced uint4 RMW (full 128B lines).
    __half* scr = (__half*)sm + wid * (64 * 72);
    const int rr = lane >> 3, ccol = (lane & 7) * 8;
#pragma unroll
    for (int p = 0; p < 2; p++) {
#pragma unroll
      for (int nt = 0; nt < 4; nt++) {
        int c = col0 + widn * 64 + nt * 16 + lr;
        float bv = bias ? bias[c] : 0.f;
#pragma unroll
        for (int ml = 0; ml < 4; ml++) {
#pragma unroll
          for (int reg = 0; reg < 4; reg++)
            scr[(ml * 16 + lq4 * 4 + reg) * 72 + nt * 16 + lr] =
                (__half)(acc[p * 4 + ml][nt][reg] + bv);
        }
      }
#pragma unroll
      for (int it = 0; it < 8; it++) {
        int r = it * 8 + rr;
        union { __half e[8]; uint4 u; } sv, ov;
        sv.u = *(const uint4*)&scr[r * 72 + ccol];
        long grow = row0 + widm * 128 + p * 64 + r;
        long idx = cOff + grow * (long)ldc + col0 + widn * 64 + ccol;
        ov.u = *(const uint4*)&Ch[idx];
#pragma unroll
        for (int e = 0; e < 8; e++)
          ov.e[e] = (__half)((float)ov.e[e] + (float)sv.e[e]);
        *(uint4*)&Ch[idx] = ov.u;
      }
    }
  } else {
    // bf16 outputs (EPI 1/4): LDS-transposed coalesced stores.
    bf16* scr = sm + wid * (64 * 72);
    const int rr = lane >> 3, ccol = (lane & 7) * 8;
#pragma unroll
    for (int p = 0; p < 2; p++) {
#pragma unroll
      for (int nt = 0; nt < 4; nt++) {
        int c = col0 + widn * 64 + nt * 16 + lr;
        float bv = bias ? bias[c] : 0.f;
#pragma unroll
        for (int ml = 0; ml < 4; ml++) {
#pragma unroll
          for (int reg = 0; reg < 4; reg++) {
            float v = acc[p * 4 + ml][nt][reg] + bv;
            if (EPI == 4) v = 0.5f * v * (1.f + fast_erff(v * 0.70710678118654752f));
            scr[(ml * 16 + lq4 * 4 + reg) * 72 + nt * 16 + lr] = (bf16)v;
          }
        }
      }
#pragma unroll
      for (int it = 0; it < 8; it++) {
        int r = it * 8 + rr;
        uint4 v = *(const uint4*)&scr[r * 72 + ccol];
        long grow = row0 + widm * 128 + p * 64 + r;
        *(uint4*)&Cb[cOff + grow * (long)ldc + col0 + widn * 64 + ccol] = v;
      }
    }
  }
}

// ---------------------------------------------------------------------------
// Generic MFMA GEMM (legacy 128x128): xW1 (AMODE1, fp16 h out via EPI=0),
// linear-out (AMODE0/EPI1), final W2 (AMODE2: fp16 h in, EPI=5 fp32 out).
// 256 threads (4 waves, 2x2), z-batched, XCD-swizzled (z-fastest).
// ---------------------------------------------------------------------------
__global__ __launch_bounds__(256) void gemm_bt(
    const void* __restrict__ Avoid, const bf16* __restrict__ Bt,
    const float* __restrict__ bias, float* __restrict__ Cf, bf16* __restrict__ Cb,
    int K, int lda, int ldb, int ldc, int EPI, int AMODE,
    long aBatch, long bBatch, int zdiv, long cOuter, long cInner) {
  __shared__ __align__(16) bf16 As0[128 * 32];
  __shared__ __align__(16) bf16 As1[128 * 32];
  __shared__ __align__(16) bf16 Bs0[128 * 32];
  __shared__ __align__(16) bf16 Bs1[128 * 32];
  const int tid = threadIdx.x;

  const int nx = gridDim.x, ny = gridDim.y, nz = gridDim.z;
  const long nwg = (long)nx * ny * nz;
  const long fid = blockIdx.x + (long)nx * (blockIdx.y + (long)ny * blockIdx.z);
  const long cq = nwg >> 3, cr = nwg & 7;
  const long xcd = fid & 7, ofs = fid >> 3;
  const long swz = (xcd < cr ? xcd * (cq + 1) : cr * (cq + 1) + (xcd - cr) * cq) + ofs;
  const int bz = (int)(swz % nz);
  const long s2 = swz / nz;
  const int bx = (int)(s2 % nx);
  const int by = (int)(s2 / nx);

  Bt += (long)bz * bBatch;
  const long cOff = (long)(bz / zdiv) * cOuter + (long)(bz % zdiv) * cInner;
  const int row0 = by * 128;
  const int col0 = bx * 128;
  const int lane = tid & 63, wid = tid >> 6;
  const int wm = (wid & 1) * 64, wn = (wid >> 1) * 64;
  const int lr = lane & 15, lk = (lane >> 4) * 8;

  floatx4 acc[4][4];
#pragma unroll
  for (int i = 0; i < 4; i++)
#pragma unroll
    for (int j = 0; j < 4; j++) acc[i][j] = {0.f, 0.f, 0.f, 0.f};

  if (AMODE == 0) {
    const bf16* A = (const bf16*)Avoid + (long)bz * aBatch;
    const bf16* pAa = A + (long)(row0 + wid * 16 + (lane >> 2)) * lda + (lane & 3) * 8;
    const bf16* pBa = Bt + (long)(col0 + wid * 16 + (lane >> 2)) * ldb + (lane & 3) * 8;
    bf16* ldsA0 = &As0[wid * 16 * 32];
    bf16* ldsA1 = &As1[wid * 16 * 32];
    bf16* ldsB0 = &Bs0[wid * 16 * 32];
    bf16* ldsB1 = &Bs1[wid * 16 * 32];
    const long a64 = (long)64 * lda, b64 = (long)64 * ldb;

    auto stage = [&](bf16* dA, bf16* dB) {
      gload_lds16(pAa, dA);
      gload_lds16(pAa + a64, dA + 64 * 32);
      gload_lds16(pBa, dB);
      gload_lds16(pBa + b64, dB + 64 * 32);
      pAa += 32; pBa += 32;
    };
    auto compute = [&](const bf16* AS, const bf16* BS) {
      short8 af[4], bfr[4];
#pragma unroll
      for (int mt = 0; mt < 4; mt++) af[mt] = *(const short8*)(&AS[(wm + mt * 16 + lr) * 32 + lk]);
#pragma unroll
      for (int nt = 0; nt < 4; nt++) bfr[nt] = *(const short8*)(&BS[(wn + nt * 16 + lr) * 32 + lk]);
#pragma unroll
      for (int mt = 0; mt < 4; mt++)
#pragma unroll
        for (int nt = 0; nt < 4; nt++)
          acc[mt][nt] = MFMA16(af[mt], bfr[nt], acc[mt][nt]);
    };

    stage(ldsA0, ldsB0);
    __syncthreads();
    for (int k0 = 0; k0 < K; k0 += 64) {
      stage(ldsA1, ldsB1);
      compute(As0, Bs0);
      __syncthreads();
      if (k0 + 64 < K) stage(ldsA0, ldsB0);
      compute(As1, Bs1);
      __syncthreads();
    }
  } else {
    const float* Af = (const float*)Avoid;
    const __half* Ah = (const __half*)Avoid;
    const int srow = tid >> 2;
    const int skcol = (tid & 3) * 8;
    const long r0 = row0 + srow, r1 = r0 + 64;
    const bf16* pB = Bt + (long)(col0 + srow) * ldb + skcol;
    const int ldsOff = srow * 32 + skcol;
    const float* pF0 = nullptr; const float* pF1 = nullptr;
    const __half* pH0 = nullptr; const __half* pH1 = nullptr;
    bool v0 = true, v1 = true;
    if (AMODE == 1) {
      int t0 = (int)(r0 & (SEQ - 1)), t1 = (int)(r1 & (SEQ - 1));
      v0 = t0 < NREAL; v1 = t1 < NREAL;
      if (!v0) t0 = 0;
      if (!v1) t1 = 0;
      pF0 = Af + ((r0 >> 12) * NREAL + t0) * DINP + skcol;
      pF1 = Af + ((r1 >> 12) * NREAL + t1) * DINP + skcol;
    } else {
      pH0 = Ah + r0 * lda + skcol;
      pH1 = Ah + r1 * lda + skcol;
    }
    for (int k0 = 0; k0 < K; k0 += 32) {
      uint4 b0 = *(const uint4*)(pB);
      uint4 b1 = *(const uint4*)(pB + (long)64 * ldb);
      pB += 32;
      uint4 a0 = {0, 0, 0, 0}, a1 = {0, 0, 0, 0};
      if (AMODE == 1) {
        if (v0) a0 = pack8(pF0);
        if (v1) a1 = pack8(pF1);
        pF0 += 32; pF1 += 32;
      } else {
        a0 = pack8h(pH0);
        a1 = pack8h(pH1);
        pH0 += 32; pH1 += 32;
      }
      __syncthreads();
      *(uint4*)(&As0[ldsOff]) = a0;
      *(uint4*)(&As0[ldsOff + 64 * 32]) = a1;
      *(uint4*)(&Bs0[ldsOff]) = b0;
      *(uint4*)(&Bs0[ldsOff + 64 * 32]) = b1;
      __syncthreads();
      short8 af[4], bfr[4];
#pragma unroll
      for (int mt = 0; mt < 4; mt++) af[mt] = *(const short8*)(&As0[(wm + mt * 16 + lr) * 32 + lk]);
#pragma unroll
      for (int nt = 0; nt < 4; nt++) bfr[nt] = *(const short8*)(&Bs0[(wn + nt * 16 + lr) * 32 + lk]);
#pragma unroll
      for (int mt = 0; mt < 4; mt++)
#pragma unroll
        for (int nt = 0; nt < 4; nt++)
          acc[mt][nt] = MFMA16(af[mt], bfr[nt], acc[mt][nt]);
    }
  }

#pragma unroll
  for (int nt = 0; nt < 4; nt++) {
    int c = col0 + wn + nt * 16 + lr;
    float bv = 0.f;
    if (bias) {
      if (EPI == 5) { if (c < 64) bv = bias[c]; }
      else bv = bias[c];
    }
#pragma unroll
    for (int mt = 0; mt < 4; mt++) {
      long rb = row0 + wm + mt * 16 + (lane >> 4) * 4;
#pragma unroll
      for (int reg = 0; reg < 4; reg++) {
        float v = acc[mt][nt][reg] + bv;
        long ri = rb + reg;
        long idx = cOff + ri * (long)ldc + c;
        if (EPI == 0) ((__half*)Cf)[idx] = (__half)fast_tanhf(v);
        else if (EPI == 1) Cb[idx] = (bf16)v;
        else if (EPI == 2) Cf[idx] += v;
        else if (EPI == 4) { float g = 0.5f * v * (1.f + fast_erff(v * 0.70710678118654752f)); Cb[idx] = (bf16)g; }
        else if (EPI == 5) {
          int bb = (int)(ri >> 12); int tt = (int)(ri & (SEQ - 1));
          if (tt < NREAL && c < 64) Cf[((long)bb * NREAL + tt) * 64 + c] = v;
        }
      }
    }
  }
}

// ---------------------------------------------------------------------------
// LayerNorm over 512 fp16 -> bf16. One wave per row, 4 rows per block.
// ---------------------------------------------------------------------------
__global__ __launch_bounds__(256) void ln_kernel(const __half* __restrict__ h,
                                                 const float* __restrict__ g,
                                                 const float* __restrict__ bta,
                                                 bf16* __restrict__ out) {
  int wid = threadIdx.x >> 6, lane = threadIdx.x & 63;
  long row = (long)blockIdx.x * 4 + wid;
  const __half* src = h + row * DM + lane * 8;
  union { __half e[8]; uint4 u; } hv;
  hv.u = *(const uint4*)(src);
  float x[8];
#pragma unroll
  for (int i = 0; i < 8; i++) x[i] = (float)hv.e[i];
  float s = 0.f, sq = 0.f;
#pragma unroll
  for (int i = 0; i < 8; i++) { s += x[i]; sq += x[i] * x[i]; }
#pragma unroll
  for (int m = 32; m >= 1; m >>= 1) { s += __shfl_xor(s, m, 64); sq += __shfl_xor(sq, m, 64); }
  float mu = s * (1.f / DM);
  float var = sq * (1.f / DM) - mu * mu;
  float rstd = rsqrtf(var + 1e-5f);
  const float* gp = g + lane * 8;
  const float* bp = bta + lane * 8;
  bf16* dst = out + row * DM + lane * 8;
#pragma unroll
  for (int i = 0; i < 8; i++)
    dst[i] = (bf16)((x[i] - mu) * rstd * gp[i] + bp[i]);
}

// ---------------------------------------------------------------------------
// Local attention, head 0. Grid (2 halves, 32 windows, GB batches).
// ---------------------------------------------------------------------------
__global__ __launch_bounds__(256) void local_attn(const bf16* __restrict__ q,
                                                  const bf16* __restrict__ k,
                                                  const bf16* __restrict__ v,
                                                  bf16* __restrict__ att) {
  int half = blockIdx.x, w = blockIdx.y, b = blockIdx.z;
  int tid = threadIdx.x, wid = tid >> 6, lane = tid & 63;
  int lr = lane & 15, lq4 = lane >> 4;
  __shared__ __align__(16) bf16 Ks[32 * 128];   // [j][d]
  __shared__ __align__(16) bf16 Vts[128 * 32];  // [d][j]
  __shared__ __align__(16) bf16 Ps[4][16 * 32]; // per-wave P scratch

  int t0 = w * 128 + half * 64 + wid * 16;
  long qbase = ((long)b * SEQ + t0 + lr) * DM;
  short8 qf[4];
#pragma unroll
  for (int ks = 0; ks < 4; ks++) qf[ks] = *(const short8*)(q + qbase + ks * 32 + lq4 * 8);

  floatx4 Oacc[8];
#pragma unroll
  for (int i = 0; i < 8; i++) Oacc[i] = {0.f, 0.f, 0.f, 0.f};
  float rs[4] = {0.f, 0.f, 0.f, 0.f};

  int keystart = w * 128 - 128;
  for (int ch = 0; ch < 12; ch++) {
    int kb = keystart + ch * 32;
    if (kb < 0 || kb >= SEQ) continue;  // uniform per block
    {
      int j = tid >> 3, d = (tid & 7) * 16;
      const bf16* ksrc = k + ((long)b * SEQ + kb + j) * DM + d;
      *(uint4*)(&Ks[j * 128 + d]) = *(const uint4*)(ksrc);
      *(uint4*)(&Ks[j * 128 + d + 8]) = *(const uint4*)(ksrc + 8);
      const bf16* vsrc = v + ((long)b * SEQ + kb + j) * DM + d;
#pragma unroll
      for (int e = 0; e < 16; e++) Vts[(d + e) * 32 + j] = vsrc[e];
    }
    __syncthreads();
    floatx4 s0 = {0.f, 0.f, 0.f, 0.f}, s1 = {0.f, 0.f, 0.f, 0.f};
#pragma unroll
    for (int ks = 0; ks < 4; ks++) {
      short8 kf0 = *(const short8*)(&Ks[(0 + lr) * 128 + ks * 32 + lq4 * 8]);
      short8 kf1 = *(const short8*)(&Ks[(16 + lr) * 128 + ks * 32 + lq4 * 8]);
      s0 = MFMA16(qf[ks], kf0, s0);
      s1 = MFMA16(qf[ks], kf1, s1);
    }
#pragma unroll
    for (int reg = 0; reg < 4; reg++) {
      float e0 = __expf(s0[reg] * 0.08838834764831845f);
      float e1 = __expf(s1[reg] * 0.08838834764831845f);
      rs[reg] += e0 + e1;
      Ps[wid][(lq4 * 4 + reg) * 32 + lr] = (bf16)e0;
      Ps[wid][(lq4 * 4 + reg) * 32 + 16 + lr] = (bf16)e1;
    }
    __syncthreads();
    short8 pf = *(const short8*)(&Ps[wid][lr * 32 + lq4 * 8]);
#pragma unroll
    for (int nt = 0; nt < 8; nt++) {
      short8 vf = *(const short8*)(&Vts[(nt * 16 + lr) * 32 + lq4 * 8]);
      Oacc[nt] = MFMA16(pf, vf, Oacc[nt]);
    }
    __syncthreads();
  }
#pragma unroll
  for (int m = 1; m < 16; m <<= 1)
#pragma unroll
    for (int reg = 0; reg < 4; reg++) rs[reg] += __shfl_xor(rs[reg], m, 64);
  long obase = ((long)b * SEQ + t0 + lq4 * 4) * DM;
#pragma unroll
  for (int nt = 0; nt < 8; nt++)
#pragma unroll
    for (int reg = 0; reg < 4; reg++)
      att[obase + (long)reg * DM + nt * 16 + lr] = (bf16)(Oacc[nt][reg] / rs[reg]);
}

// ---------------------------------------------------------------------------
// Linear-attn q-softmax: qp[z][t][128] = softmax(q_head)*d^-0.5, z=lb*3+h2
// ---------------------------------------------------------------------------
__global__ __launch_bounds__(256) void qp_softmax(const bf16* __restrict__ q, bf16* __restrict__ qp) {
  int wid = threadIdx.x >> 6, lane = threadIdx.x & 63;
  long task = (long)blockIdx.x * 4 + wid;
  int tt = (int)(task & (SEQ - 1));
  int z6 = (int)(task >> 12);
  int lb = z6 / 3, h2 = z6 % 3;
  const bf16* src = q + ((long)lb * SEQ + tt) * DM + (h2 + 1) * 128 + lane * 2;
  float x0 = (float)src[0], x1 = (float)src[1];
  float m = fmaxf(x0, x1);
#pragma unroll
  for (int s = 32; s >= 1; s >>= 1) m = fmaxf(m, __shfl_xor(m, s, 64));
  float e0 = __expf(x0 - m), e1 = __expf(x1 - m);
  float sm = e0 + e1;
#pragma unroll
  for (int s = 32; s >= 1; s >>= 1) sm += __shfl_xor(sm, s, 64);
  float inv = 0.08838834764831845f / sm;
  bf16* dst = qp + task * 128 + lane * 2;
  dst[0] = (bf16)(e0 * inv);
  dst[1] = (bf16)(e1 * inv);
}

// ---------------------------------------------------------------------------
// k column stats, phase 1: per-(z, 128-row chunk) column max and exp-sum.
// ---------------------------------------------------------------------------
__global__ __launch_bounds__(128) void kstats_part(const bf16* __restrict__ k,
                                                   float* __restrict__ part, int lOff) {
  int chunk = blockIdx.x, z = blockIdx.y;
  int lb = z / 3, h2 = z % 3, ch = (h2 + 1) * 128;
  int d = threadIdx.x;
  const bf16* base = k + ((long)lb * SEQ + chunk * 128) * DM + ch + d;
  float m = -1e30f;
#pragma unroll 4
  for (int t = 0; t < 128; t++) m = fmaxf(m, (float)base[(long)t * DM]);
  float l = 0.f;
#pragma unroll 4
  for (int t = 0; t < 128; t++) l += __expf((float)base[(long)t * DM] - m);
  int idx = (z * 32 + chunk) * 128 + d;
  part[idx] = m;
  part[lOff + idx] = l;
}

// phase 2: combine 32 chunk stats -> kml[z*256+d]=M, +128=L
__global__ __launch_bounds__(128) void kstats_comb(const float* __restrict__ part,
                                                   float* __restrict__ kml, int lOff) {
  int z = blockIdx.x, d = threadIdx.x;
  float M = -1e30f;
#pragma unroll 4
  for (int c = 0; c < 32; c++) M = fmaxf(M, part[(z * 32 + c) * 128 + d]);
  float L = 0.f;
#pragma unroll 4
  for (int c = 0; c < 32; c++) {
    int i = (z * 32 + c) * 128 + d;
    L += part[lOff + i] * __expf(part[i] - M);
  }
  kml[z * 256 + d] = M;
  kml[z * 256 + 128 + d] = L;
}

// ---------------------------------------------------------------------------
// ctx via MFMA: part[z][chunk][e*128+d] = sum_{t in 512-chunk} v[t][e]*k'[t][d]
// ---------------------------------------------------------------------------
__global__ __launch_bounds__(256) void ctx_mfma(const bf16* __restrict__ k,
                                                const bf16* __restrict__ v,
                                                const float* __restrict__ kml,
                                                float* __restrict__ part) {
  int chunk = blockIdx.x, z = blockIdx.y;
  int lb = z / 3, h2 = z % 3, ch = (h2 + 1) * 128;
  int tid = threadIdx.x, lane = tid & 63, wid = tid >> 6;
  const int wm = (wid & 1) * 64, wn = (wid >> 1) * 64;
  const int lr = lane & 15, lk = (lane >> 4) * 8;
  __shared__ float ml2[128];
  __shared__ __align__(16) bf16 Vt[128 * CS];
  __shared__ __align__(16) bf16 Kt[128 * CS];
  if (tid < 128)
    ml2[tid] = kml[z * 256 + tid] + logf(kml[z * 256 + 128 + tid]);

  int j = tid >> 3, d0 = (tid & 7) * 16;
  const bf16* vsrc = v + ((long)lb * SEQ + chunk * 512 + j) * DM + ch + d0;
  const bf16* ksrc = k + ((long)lb * SEQ + chunk * 512 + j) * DM + ch + d0;

  floatx4 acc[4][4];
#pragma unroll
  for (int i = 0; i < 4; i++)
#pragma unroll
    for (int jj = 0; jj < 4; jj++) acc[i][jj] = {0.f, 0.f, 0.f, 0.f};

  for (int s = 0; s < 16; s++) {
    union { bf16 h[16]; uint4 u[2]; } va, ka;
    va.u[0] = *(const uint4*)(vsrc); va.u[1] = *(const uint4*)(vsrc + 8);
    ka.u[0] = *(const uint4*)(ksrc); ka.u[1] = *(const uint4*)(ksrc + 8);
    vsrc += (long)32 * DM; ksrc += (long)32 * DM;
    __syncthreads();
#pragma unroll
    for (int e = 0; e < 16; e++) {
      Vt[(d0 + e) * CS + j] = va.h[e];
      Kt[(d0 + e) * CS + j] = (bf16)__expf((float)ka.h[e] - ml2[d0 + e]);
    }
    __syncthreads();
    short8 af[4], bfr[4];
#pragma unroll
    for (int mt = 0; mt < 4; mt++) af[mt] = *(const short8*)(&Vt[(wm + mt * 16 + lr) * CS + lk]);
#pragma unroll
    for (int nt = 0; nt < 4; nt++) bfr[nt] = *(const short8*)(&Kt[(wn + nt * 16 + lr) * CS + lk]);
#pragma unroll
    for (int mt = 0; mt < 4; mt++)
#pragma unroll
      for (int nt = 0; nt < 4; nt++)
        acc[mt][nt] = MFMA16(af[mt], bfr[nt], acc[mt][nt]);
  }

  float* dst = part + ((long)z * 8 + chunk) * 16384;
#pragma unroll
  for (int nt = 0; nt < 4; nt++) {
    int c = wn + nt * 16 + lr;
#pragma unroll
    for (int mt = 0; mt < 4; mt++) {
      int rb = wm + mt * 16 + (lane >> 4) * 4;
#pragma unroll
      for (int reg = 0; reg < 4; reg++)
        dst[(rb + reg) * 128 + c] = acc[mt][nt][reg];
    }
  }
}

__global__ __launch_bounds__(256) void ctx_reduce(const float* __restrict__ part, bf16* __restrict__ ctxT) {
  long i = (long)blockIdx.x * 256 + threadIdx.x;
  int z = (int)(i >> 14);
  int off = (int)(i & 16383);
  float s = 0.f;
#pragma unroll
  for (int c = 0; c < 8; c++) s += part[(((long)z * 8 + c) << 14) + off];
  ctxT[i] = (bf16)s;
}

// ---------------------------------------------------------------------------
extern "C" void kernel_launch(void* const* d_in, const int* in_sizes, int n_in,
                              void* d_out, int out_size, void* d_ws, size_t ws_size,
                              hipStream_t stream) {
  float* outp = (float*)d_out;

  // ---- adaptive arena: pick largest GB in {8,4,2} that fits ws_size ----
  long offH = 0;
  int GB = 0;
  long offLNG, offQ, offK, offV, offATT, offCTXP, offCTXT, offKML, offWT, need;
  for (int gb = 8; gb >= 2; gb >>= 1) {
    long sLN = (long)gb * 4194304;
    offLNG = 67108864L;
    offQ   = offLNG + sLN;
    offK   = offQ + sLN;
    offV   = offK + sLN;
    offATT = offV + sLN;
    offCTXP= offATT + sLN;
    offCTXT= offCTXP + (long)gb * 1572864;
    offKML = offCTXT + (long)gb * 98304;
    offWT  = offKML + (long)gb * 3072;
    need   = offWT + 6553600L;
    if ((size_t)need <= ws_size) { GB = gb; break; }
  }
  if (GB == 0) {
    beacon<<<(out_size + 255) / 256, 256, 0, stream>>>(outp, out_size);
    return;
  }
  const int NG = NBAT / GB;            // groups
  const long GR = (long)GB * SEQ;      // rows per group
  const int NZ = GB * 3;               // linear-attn (batch,head) pairs per group

  const float* x   = (const float*)d_in[0];
  const float* W1  = (const float*)d_in[1];
  const float* b1  = (const float*)d_in[2];
  const float* g1  = (const float*)d_in[3];
  const float* be1 = (const float*)d_in[4];
  const float* Wq  = (const float*)d_in[5];
  const float* Wk  = (const float*)d_in[6];
  const float* Wv  = (const float*)d_in[7];
  const float* Wo  = (const float*)d_in[8];
  const float* bo  = (const float*)d_in[9];
  const float* g2  = (const float*)d_in[10];
  const float* be2 = (const float*)d_in[11];
  const float* Wf1 = (const float*)d_in[12];
  const float* bf1 = (const float*)d_in[13];
  const float* Wf2 = (const float*)d_in[14];
  const float* bf2 = (const float*)d_in[15];
  const float* W2  = (const float*)d_in[16];
  const float* b2  = (const float*)d_in[17];

  char* ws = (char*)d_ws;
  __half* h  = (__half*)(ws + offH);   // fp16 residual stream (32MB)
  bf16* lnG  = (bf16*)(ws + offLNG);
  bf16* qp   = (bf16*)(ws + offLNG);   // overlays lnG (lnG dead after QKV; qp dead in FFN)
  bf16* qb   = (bf16*)(ws + offQ);
  bf16* kb   = (bf16*)(ws + offK);
  bf16* vb   = (bf16*)(ws + offV);
  bf16* attb = (bf16*)(ws + offATT);
  bf16* ff1g = (bf16*)(ws + offQ);     // overlays q..attn (dead in FFN phase)
  float* ctxp= (float*)(ws + offCTXP);
  bf16* ctxT = (bf16*)(ws + offCTXT);
  float* kml = (float*)(ws + offKML);
  bf16* wt   = (bf16*)(ws + offWT);
  bf16* wqt  = wt + 65536;
  bf16* wot  = wt + 851968;
  bf16* wf1t = wt + 1114112;
  bf16* wf2t = wt + 2162688;
  bf16* w2t  = wt + 3211264;
  const int lOff = NZ * 32 * 128;      // kstats l-plane offset within ctxp

  // ---- all weight transposes (fp32 -> bf16, [Npad][K] K-contiguous) ----
  transpose8<<<dim3(32, 32, 8), 256, 0, stream>>>(W1, Wq, Wk, Wv, Wo, Wf1, Wf2, W2, wt);

  // ---- h = tanh(xpad @ W1 + b1) fp16; pad rows handled in A staging ----
  gemm_bt<<<dim3(4, 256, 1), 256, 0, stream>>>(x, wt, b1, (float*)h, nullptr,
      DINP, DINP, DINP, DM, 0, 1, 0, 0, 1, 0, 0);

  // ---- attention, NG groups of GB batches ----
  for (int g = 0; g < NG; g++) {
    __half* hg = h + (long)g * GR * DM;
    ln_kernel<<<(int)(GR / 4), 256, 0, stream>>>(hg, g1, be1, lnG);
    // Q,K,V in one z=3 batched launch (outputs land in qb,kb,vb = contiguous)
    gemm256<<<dim3(2, (int)(GR / 256), 3), 512, 0, stream>>>(lnG, wqt, nullptr, nullptr, qb,
        DM, DM, DM, DM, 1,
        0L, 262144L, 3, 0L, GR * DM);

    local_attn<<<dim3(2, 32, GB), 256, 0, stream>>>(qb, kb, vb, attb);

    qp_softmax<<<NZ * 1024, 256, 0, stream>>>(qb, qp);
    kstats_part<<<dim3(32, NZ), 128, 0, stream>>>(kb, ctxp, lOff);
    kstats_comb<<<NZ, 128, 0, stream>>>(ctxp, kml, lOff);
    ctx_mfma<<<dim3(8, NZ), 256, 0, stream>>>(kb, vb, kml, ctxp);
    ctx_reduce<<<NZ * 64, 256, 0, stream>>>(ctxp, ctxT);
    gemm_bt<<<dim3(1, 32, NZ), 256, 0, stream>>>(qp, ctxT, nullptr, nullptr, attb + 128,
        128, 128, 128, DM, 1, 0,
        (long)SEQ * 128, 16384L, 3, (long)SEQ * DM, 128L);

    // h += attn @ Wo + bo : 256-tile, coalesced fp16 RMW
    gemm256<<<dim3(2, (int)(GR / 256), 1), 512, 0, stream>>>(attb, wot, bo, hg, nullptr,
        DM, DM, DM, DM, 2, 0, 0, 1, 0, 0);
  }

  // ---- FFN, NG groups ----
  for (int g = 0; g < NG; g++) {
    __half* hg = h + (long)g * GR * DM;
    ln_kernel<<<(int)(GR / 4), 256, 0, stream>>>(hg, g2, be2, lnG);
    gemm256<<<dim3(8, (int)(GR / 256), 1), 512, 0, stream>>>(lnG, wf1t, bf1, nullptr, ff1g,
        DM, DM, DM, DFF, 4, 0, 0, 1, 0, 0);
    // h += gelu(ff1) @ Wf2 + bf2 : 256-tile, coalesced fp16 RMW
    gemm256<<<dim3(2, (int)(GR / 256), 1), 512, 0, stream>>>(ff1g, wf2t, bf2, hg, nullptr,
        DFF, DFF, DFF, DM, 2, 0, 0, 1, 0, 0);
  }

  // ---- out = (h @ W2 + b2)[:, :3000, :] -> d_out fp32 (h read as fp16) ----
  gemm_bt<<<dim3(1, 256, 1), 256, 0, stream>>>(h, w2t, b2, outp, nullptr,
      DM, DM, DM, 64, 5, 2, 0, 0, 1, 0, 0);
}